// Round 5
// baseline (269.617 us; speedup 1.0000x reference)
//
#include <hip/hip_runtime.h>
#include <hip/hip_bf16.h>
#include <math.h>

#define B_  16
#define N_  16
#define T_  48
#define C_  512
#define H_  8
#define HD_ 64
#define L_  768
#define BL_ 12288

typedef __attribute__((ext_vector_type(8))) short b16x8;
typedef __attribute__((ext_vector_type(4))) float f32x4;
typedef __attribute__((ext_vector_type(2))) unsigned int u32x2;

__device__ __forceinline__ short f2b(float f) {
  __hip_bfloat16 h = __float2bfloat16(f);
  return *reinterpret_cast<short*>(&h);
}
// packed f32x2 -> bf16x2 (RNE), single VALU op
__device__ __forceinline__ unsigned cvt_pk_bf16(float a, float b) {
  unsigned d;
  asm("v_cvt_pk_bf16_f32 %0, %1, %2" : "=v"(d) : "v"(a), "v"(b));
  return d;
}
// 2^x, single transcendental VALU op (biases/scales pre-folded by log2e)
__device__ __forceinline__ float ex2(float x) {
  float d;
  asm("v_exp_f32 %0, %1" : "=v"(d) : "v"(x));
  return d;
}

// ---------------------------------------------------------------------------
// prep: blocks [0,3072) cast x fp32->bf16; blocks [3072,4096) cast+transpose
// weights into WT[mat][n][k] (Wq pre-scaled by log2(e)/8 for exp2 softmax).
// ---------------------------------------------------------------------------
__global__ __launch_bounds__(256) void prep_kernel(
    const float* __restrict__ x,
    const float* __restrict__ Wq, const float* __restrict__ Wk,
    const float* __restrict__ Wv, const float* __restrict__ Wo,
    short* __restrict__ xb, short* __restrict__ WT)
{
  __shared__ float tile[32][33];
  int blk = blockIdx.x;
  int tid = threadIdx.x;
  if (blk < 3072) {
    int i = blk * 256 + tid;
    const float4* src = (const float4*)(x + (size_t)i * 8);
    float4 a = src[0], b = src[1];
    short tmp[8] = {f2b(a.x), f2b(a.y), f2b(a.z), f2b(a.w),
                    f2b(b.x), f2b(b.y), f2b(b.z), f2b(b.w)};
    *(b16x8*)(xb + (size_t)i * 8) = *(b16x8*)tmp;
  } else {
    int idx = blk - 3072;
    int mat = idx >> 8, rem = idx & 255;
    const float* W = (mat == 0) ? Wq : (mat == 1) ? Wk : (mat == 2) ? Wv : Wo;
    float scale = (mat == 0) ? 0.18033688f : 1.0f;   // log2(e)/8
    int k0 = (rem >> 4) * 32, n0 = (rem & 15) * 32;
    int tx = tid & 31, ty = tid >> 5;
    for (int i = ty; i < 32; i += 8) tile[i][tx] = W[(size_t)(k0 + i) * 512 + n0 + tx];
    __syncthreads();
    short* dst = WT + (size_t)mat * 262144;
    for (int i = ty; i < 32; i += 8)
      dst[(size_t)(n0 + i) * 512 + k0 + tx] = f2b(tile[tx][i] * scale);
  }
}

// ---------------------------------------------------------------------------
// QKV GEMM, time-major permuted M-rows (rr = pt*16+pn) + LDS-staged epilogue.
//   q2,k2: [b][h][t][n][d]   vT2: [b][h][d][t][n]
// ---------------------------------------------------------------------------
__global__ __launch_bounds__(256) void qkv_kernel(
    const short* __restrict__ xb, const short* __restrict__ WT,
    short* __restrict__ q2, short* __restrict__ k2, short* __restrict__ vT2)
{
  __shared__ short smem[8192];              // As/Bs during K-loop; Ls in epilogue
  short (*As)[32] = (short(*)[32])smem;
  short (*Bs)[32] = (short(*)[32])(smem + 4096);
  int tid = threadIdx.x;
  int w = tid >> 6, lane = tid & 63, n16 = lane & 15, quad = lane >> 4;
  int bm = blockIdx.x, bn = blockIdx.y;
  int mat = bn >> 2;
  int ncol0 = (bn & 3) * 128;
  const short* Wt = WT + (size_t)mat * 262144;
  int bq = bm / 6;
  int rr0 = (bm % 6) * 128;

  f32x4 zero4 = {0.f, 0.f, 0.f, 0.f};
  f32x4 acc[4][4];
  #pragma unroll
  for (int mt = 0; mt < 4; ++mt)
    #pragma unroll
    for (int nt = 0; nt < 4; ++nt) acc[mt][nt] = zero4;

  int srow = tid >> 1, sch = (tid & 1) * 16;
  int rr = rr0 + srow;
  int pt = rr >> 4, pn = rr & 15;           // permuted row -> l = pn*48+pt
  const short* ga = xb + ((size_t)bq * 768 + pn * 48 + pt) * 512 + sch;
  const short* gb = Wt + (size_t)(ncol0 + srow) * 512 + sch;
  int wm = (w >> 1) * 64, wn = (w & 1) * 64;

  for (int kt = 0; kt < 16; ++kt) {
    b16x8 a0 = *(const b16x8*)(ga);
    b16x8 a1 = *(const b16x8*)(ga + 8);
    b16x8 b0 = *(const b16x8*)(gb);
    b16x8 b1 = *(const b16x8*)(gb + 8);
    ga += 32; gb += 32;
    __syncthreads();
    *(b16x8*)&As[srow][sch]     = a0;
    *(b16x8*)&As[srow][sch + 8] = a1;
    *(b16x8*)&Bs[srow][sch]     = b0;
    *(b16x8*)&Bs[srow][sch + 8] = b1;
    __syncthreads();
    b16x8 af[4], bf[4];
    #pragma unroll
    for (int mt = 0; mt < 4; ++mt) af[mt] = *(const b16x8*)&As[wm + mt * 16 + n16][quad * 8];
    #pragma unroll
    for (int nt = 0; nt < 4; ++nt) bf[nt] = *(const b16x8*)&Bs[wn + nt * 16 + n16][quad * 8];
    #pragma unroll
    for (int mt = 0; mt < 4; ++mt)
      #pragma unroll
      for (int nt = 0; nt < 4; ++nt)
        acc[mt][nt] = __builtin_amdgcn_mfma_f32_16x16x32_bf16(af[mt], bf[nt], acc[mt][nt], 0, 0, 0);
  }

  // epilogue: 4 chunks of 32 tile-rows staged through LDS, vector stores out
  short (*Ls)[136] = (short(*)[136])smem;   // 32 x 136 (pad: aligned, spread banks)
  for (int c = 0; c < 4; ++c) {
    __syncthreads();
    if ((w >> 1) == (c >> 1)) {             // waves owning rows 32c..32c+31
      int mtb = (c & 1) * 2;
      #pragma unroll
      for (int mi = 0; mi < 2; ++mi) {
        #pragma unroll
        for (int nt = 0; nt < 4; ++nt)
          #pragma unroll
          for (int r = 0; r < 4; ++r)
            Ls[mi * 16 + quad * 4 + r][wn + nt * 16 + n16] = f2b(acc[mtb + mi][nt][r]);
      }
    }
    __syncthreads();
    int rrc = rr0 + c * 32;
    if (mat != 2) {
      short* dst = (mat == 0) ? q2 : k2;
      int row = tid >> 3, c0 = (tid & 7) * 16;
      int hhg = (ncol0 + c0) >> 6, d0 = (ncol0 + c0) & 63;
      short* dp = dst + ((size_t)(bq * 8 + hhg) * 768 + rrc + row) * 64 + d0;
      *(b16x8*)dp       = *(b16x8*)&Ls[row][c0];
      *(b16x8*)(dp + 8) = *(b16x8*)&Ls[row][c0 + 8];
    } else {
      int cp = tid & 63, r8 = (tid >> 6) * 8;
      int c0 = 2 * cp;
      int hhg = (ncol0 + c0) >> 6, d0 = (ncol0 + c0) & 63;
      short t0[8], t1[8];
      #pragma unroll
      for (int j = 0; j < 8; ++j) { t0[j] = Ls[r8 + j][c0]; t1[j] = Ls[r8 + j][c0 + 1]; }
      short* dp = vT2 + ((size_t)(bq * 8 + hhg) * 64 + d0) * 768 + rrc + r8;
      *(b16x8*)dp         = *(b16x8*)t0;
      *(b16x8*)(dp + 768) = *(b16x8*)t1;
    }
  }
}

// ---------------------------------------------------------------------------
// Attention (R9 core): R7's key-parity split (4 waves/block = 2 q-pairs x
// 2 key-halves; no-max softmax => partial (O, ps) merge by pure LDS add),
// but WITHOUT the fatal launch_bounds(256,6) reg cap: (256,4) allows the
// ~112-reg wave -> no spill, 4 waves/SIMD, 8 chains/SIMD (R6 had 6).
// Plus exp2 folding: Wq/biases pre-scaled by log2e -> v_exp_f32 direct.
// ---------------------------------------------------------------------------
__global__ __launch_bounds__(256, 4) void attn_kernel(
    const short* __restrict__ q2, const short* __restrict__ k2,
    const short* __restrict__ vT2,
    const float* __restrict__ relT, const float* __restrict__ relP,
    short* __restrict__ yatt)
{
  __shared__ float btL[2][96];
  __shared__ float mO[2][8][4][64];         // [pair][acc][r][lane] partial O
  __shared__ float mS[2][2][64];            // [pair][A/B][lane] partial ps

  const float LOG2E = 1.44269504f;
  int tid = threadIdx.x;
  int wv2 = tid >> 6, lane = tid & 63, n16 = lane & 15, quad = lane >> 4;
  int p  = wv2 & 1;                         // pair-in-block
  int kh = wv2 >> 1;                        // key-parity half (0=even kt2, 1=odd)
  int blk = blockIdx.x;
  int h = blk & 7;                          // XCD-locality
  int g = blk >> 3;
  int pg = g % 12, b = g / 12;
  int pair = pg * 2 + p;
  int qtA = pair, qtB = 47 - pair;
  int nA = (qtA + 2) >> 1, nB = (qtB + 2) >> 1;

  if (wv2 < 2) {
    btL[wv2][lane] = relT[(lane < 95 ? lane : 94) * 8 + h] * LOG2E;
    if (lane < 32)
      btL[wv2][64 + lane] = relT[((64 + lane) < 95 ? 64 + lane : 94) * 8 + h] * LOG2E;
  }
  __syncthreads();

  // swapped layout: reg r = key particle quad*4+r, lane n16 = q particle
  // bias_p[q][k] = relP[k - q + 15]
  float bpT[4];
  #pragma unroll
  for (int r = 0; r < 4; ++r)
    bpT[r] = relP[(quad * 4 + r - n16 + 15) * 8 + h] * LOG2E;

  size_t bh = (size_t)(b * 8 + h);
  const short* qb = q2 + bh * 49152;
  const short* kb = k2 + bh * 49152;
  const short* vb = vT2 + bh * 49152;

  b16x8 qA0 = *(const b16x8*)(qb + (qtA * 16 + n16) * 64 + quad * 8);
  b16x8 qA1 = *(const b16x8*)(qb + (qtA * 16 + n16) * 64 + quad * 8 + 32);
  b16x8 qB0 = *(const b16x8*)(qb + (qtB * 16 + n16) * 64 + quad * 8);
  b16x8 qB1 = *(const b16x8*)(qb + (qtB * 16 + n16) * 64 + quad * 8 + 32);

  f32x4 zero4 = {0.f, 0.f, 0.f, 0.f};
  f32x4 oA[4], oB[4];
  float psA = 0.f, psB = 0.f;
  #pragma unroll
  for (int nt = 0; nt < 4; ++nt) { oA[nt] = zero4; oB[nt] = zero4; }

  b16x8 kfa[4], kfb[4], vfa[4], vfb[4];
  auto loadKV = [&](int kt2, b16x8* kf, b16x8* vf) {
    const short* kp = kb + (size_t)(kt2 * 32 + n16) * 64 + quad * 8;
    kf[0] = *(const b16x8*)kp;
    kf[1] = *(const b16x8*)(kp + 32);
    kf[2] = *(const b16x8*)(kp + 1024);
    kf[3] = *(const b16x8*)(kp + 1024 + 32);
    const short* vp = vb + (size_t)n16 * 768 + kt2 * 32 + quad * 8;
    vf[0] = *(const b16x8*)vp;
    vf[1] = *(const b16x8*)(vp + 16 * 768);
    vf[2] = *(const b16x8*)(vp + 32 * 768);
    vf[3] = *(const b16x8*)(vp + 48 * 768);
  };

  // exp2 + bias on S^T tile pair, pack to the PV A-fragment in-register.
  auto exp_pack = [&](const f32x4& s0, const f32x4& s1, float bt0, float bt1,
                      float& ps) -> b16x8 {
    float c00 = bt0 + bpT[0], c01 = bt0 + bpT[1];
    float c02 = bt0 + bpT[2], c03 = bt0 + bpT[3];
    float c10 = bt1 + bpT[0], c11 = bt1 + bpT[1];
    float c12 = bt1 + bpT[2], c13 = bt1 + bpT[3];
    float e00 = ex2(s0[0] + c00);
    float e01 = ex2(s0[1] + c01);
    float e02 = ex2(s0[2] + c02);
    float e03 = ex2(s0[3] + c03);
    float e10 = ex2(s1[0] + c10);
    float e11 = ex2(s1[1] + c11);
    float e12 = ex2(s1[2] + c12);
    float e13 = ex2(s1[3] + c13);
    ps += ((e00 + e01) + (e02 + e03)) + ((e10 + e11) + (e12 + e13));
    unsigned p0 = cvt_pk_bf16(e00, e01);
    unsigned p1 = cvt_pk_bf16(e02, e03);
    unsigned p2 = cvt_pk_bf16(e10, e11);
    unsigned p3 = cvt_pk_bf16(e12, e13);
    u32x2 a02 = __builtin_amdgcn_permlane32_swap(p0, p2, false, false);
    u32x2 z02 = __builtin_amdgcn_permlane16_swap(a02.x, a02.y, false, false);
    u32x2 a13 = __builtin_amdgcn_permlane32_swap(p1, p3, false, false);
    u32x2 z13 = __builtin_amdgcn_permlane16_swap(a13.x, a13.y, false, false);
    union { unsigned u[4]; b16x8 v; } r;
    r.u[0] = z02.x;
    r.u[1] = z13.x;
    r.u[2] = z02.y;
    r.u[3] = z13.y;
    return r.v;
  };

  auto step = [&](int kt2, const b16x8* kf, const b16x8* vf) {
    int kt0 = kt2 * 2;
    bool doA = kt2 < nA;                    // wave-uniform
    f32x4 sB0 = zero4, sB1 = zero4;
    sB0 = __builtin_amdgcn_mfma_f32_16x16x32_bf16(kf[0], qB0, sB0, 0, 0, 0);
    sB0 = __builtin_amdgcn_mfma_f32_16x16x32_bf16(kf[1], qB1, sB0, 0, 0, 0);
    sB1 = __builtin_amdgcn_mfma_f32_16x16x32_bf16(kf[2], qB0, sB1, 0, 0, 0);
    sB1 = __builtin_amdgcn_mfma_f32_16x16x32_bf16(kf[3], qB1, sB1, 0, 0, 0);
    f32x4 sA0 = zero4, sA1 = zero4;
    if (doA) {
      sA0 = __builtin_amdgcn_mfma_f32_16x16x32_bf16(kf[0], qA0, sA0, 0, 0, 0);
      sA0 = __builtin_amdgcn_mfma_f32_16x16x32_bf16(kf[1], qA1, sA0, 0, 0, 0);
      sA1 = __builtin_amdgcn_mfma_f32_16x16x32_bf16(kf[2], qA0, sA1, 0, 0, 0);
      sA1 = __builtin_amdgcn_mfma_f32_16x16x32_bf16(kf[3], qA1, sA1, 0, 0, 0);
    }
    float btB0 = (kt0 <= qtB) ? btL[p][kt0 - qtB + 47] : -1e30f;
    float btB1 = (kt0 + 1 <= qtB) ? btL[p][kt0 + 1 - qtB + 47] : -1e30f;
    b16x8 pfB = exp_pack(sB0, sB1, btB0, btB1, psB);
    #pragma unroll
    for (int nt = 0; nt < 4; ++nt)
      oB[nt] = __builtin_amdgcn_mfma_f32_16x16x32_bf16(pfB, vf[nt], oB[nt], 0, 0, 0);
    if (doA) {
      float btA0 = (kt0 <= qtA) ? btL[p][kt0 - qtA + 47] : -1e30f;
      float btA1 = (kt0 + 1 <= qtA) ? btL[p][kt0 + 1 - qtA + 47] : -1e30f;
      b16x8 pfA = exp_pack(sA0, sA1, btA0, btA1, psA);
      #pragma unroll
      for (int nt = 0; nt < 4; ++nt)
        oA[nt] = __builtin_amdgcn_mfma_f32_16x16x32_bf16(pfA, vf[nt], oA[nt], 0, 0, 0);
    }
  };

  // key-parity split: this wave handles kt2 = kh, kh+2, kh+4, ...
  loadKV(kh, kfa, vfa);
  for (int kt2 = kh; kt2 < nB; kt2 += 4) {
    if (kt2 + 2 < nB) loadKV(kt2 + 2, kfb, vfb);
    step(kt2, kfa, vfa);
    if (kt2 + 2 < nB) {
      if (kt2 + 4 < nB) loadKV(kt2 + 4, kfa, vfa);
      step(kt2 + 2, kfb, vfb);
    }
  }

  // merge the two key-halves through LDS (pure add: no-max softmax)
  if (kh == 1) {
    #pragma unroll
    for (int nt = 0; nt < 4; ++nt)
      #pragma unroll
      for (int r = 0; r < 4; ++r) {
        mO[p][nt][r][lane]     = oA[nt][r];
        mO[p][nt + 4][r][lane] = oB[nt][r];
      }
    mS[p][0][lane] = psA;
    mS[p][1][lane] = psB;
  }
  __syncthreads();
  if (kh == 1) return;
  #pragma unroll
  for (int nt = 0; nt < 4; ++nt)
    #pragma unroll
    for (int r = 0; r < 4; ++r) {
      oA[nt][r] += mO[p][nt][r][lane];
      oB[nt][r] += mO[p][nt + 4][r][lane];
    }
  psA += mS[p][0][lane];
  psB += mS[p][1][lane];

  // denom: per-lane partial (q = n16, keys split across quads) -> full sum
  psA += __shfl_xor(psA, 16); psA += __shfl_xor(psA, 32);
  psB += __shfl_xor(psB, 16); psB += __shfl_xor(psB, 32);
  float invA = 1.0f / psA, invB = 1.0f / psB;
  // redistribute to C-layout rows: lane needs 1/ps for q = quad*4+r
  float pnA[4], pnB[4];
  #pragma unroll
  for (int r = 0; r < 4; ++r) {
    pnA[r] = __shfl(invA, quad * 4 + r);
    pnB[r] = __shfl(invB, quad * 4 + r);
  }

  #pragma unroll
  for (int nt = 0; nt < 4; ++nt) {
    int c = h * 64 + nt * 16 + n16;
    #pragma unroll
    for (int r = 0; r < 4; ++r) {
      int qn = quad * 4 + r;
      yatt[((size_t)b * 768 + qn * 48 + qtA) * 512 + c] = f2b(oA[nt][r] * pnA[r]);
      yatt[((size_t)b * 768 + qn * 48 + qtB) * 512 + c] = f2b(oB[nt][r] * pnB[r]);
    }
  }
}

// ---------------------------------------------------------------------------
// proj: yatt(12288x512,bf16) @ WoT -> out fp32
// ---------------------------------------------------------------------------
__global__ __launch_bounds__(256) void proj_kernel(
    const short* __restrict__ yatt, const short* __restrict__ WT,
    float* __restrict__ out)
{
  __shared__ short As[128][32];
  __shared__ short Bs[128][32];
  int tid = threadIdx.x;
  int w = tid >> 6, lane = tid & 63, n16 = lane & 15, quad = lane >> 4;
  int row0 = blockIdx.x * 128;
  int ncol0 = blockIdx.y * 128;
  const short* Wt = WT + (size_t)3 * 262144;

  f32x4 zero4 = {0.f, 0.f, 0.f, 0.f};
  f32x4 acc[4][4];
  #pragma unroll
  for (int mt = 0; mt < 4; ++mt)
    #pragma unroll
    for (int nt = 0; nt < 4; ++nt) acc[mt][nt] = zero4;

  int srow = tid >> 1, sch = (tid & 1) * 16;
  const short* ga = yatt + (size_t)(row0 + srow) * 512 + sch;
  const short* gb = Wt + (size_t)(ncol0 + srow) * 512 + sch;
  int wm = (w >> 1) * 64, wn = (w & 1) * 64;

  for (int kt = 0; kt < 16; ++kt) {
    b16x8 a0 = *(const b16x8*)(ga);
    b16x8 a1 = *(const b16x8*)(ga + 8);
    b16x8 b0 = *(const b16x8*)(gb);
    b16x8 b1 = *(const b16x8*)(gb + 8);
    ga += 32; gb += 32;
    __syncthreads();
    *(b16x8*)&As[srow][sch]     = a0;
    *(b16x8*)&As[srow][sch + 8] = a1;
    *(b16x8*)&Bs[srow][sch]     = b0;
    *(b16x8*)&Bs[srow][sch + 8] = b1;
    __syncthreads();
    b16x8 af[4], bf[4];
    #pragma unroll
    for (int mt = 0; mt < 4; ++mt) af[mt] = *(const b16x8*)&As[wm + mt * 16 + n16][quad * 8];
    #pragma unroll
    for (int nt = 0; nt < 4; ++nt) bf[nt] = *(const b16x8*)&Bs[wn + nt * 16 + n16][quad * 8];
    #pragma unroll
    for (int mt = 0; mt < 4; ++mt)
      #pragma unroll
      for (int nt = 0; nt < 4; ++nt)
        acc[mt][nt] = __builtin_amdgcn_mfma_f32_16x16x32_bf16(af[mt], bf[nt], acc[mt][nt], 0, 0, 0);
  }

  #pragma unroll
  for (int mt = 0; mt < 4; ++mt) {
    int rowb = row0 + wm + mt * 16 + quad * 4;
    #pragma unroll
    for (int nt = 0; nt < 4; ++nt) {
      int colg = ncol0 + wn + nt * 16 + n16;
      #pragma unroll
      for (int r = 0; r < 4; ++r)
        out[(size_t)(rowb + r) * 512 + colg] = acc[mt][nt][r];
    }
  }
}

// ---------------------------------------------------------------------------
extern "C" void kernel_launch(void* const* d_in, const int* in_sizes, int n_in,
                              void* d_out, int out_size, void* d_ws, size_t ws_size,
                              hipStream_t stream) {
  const float* x    = (const float*)d_in[0];
  const float* Wq   = (const float*)d_in[1];
  const float* Wk   = (const float*)d_in[2];
  const float* Wv   = (const float*)d_in[3];
  const float* Wo   = (const float*)d_in[4];
  const float* relT = (const float*)d_in[5];
  const float* relP = (const float*)d_in[6];

  char* wsb = (char*)d_ws;
  const size_t SZ = (size_t)BL_ * C_ * 2;
  short* xb  = (short*)(wsb);
  short* WT  = (short*)(wsb + SZ);
  short* qb  = (short*)(wsb + SZ + 2097152);
  short* kb  = (short*)(wsb + 2 * SZ + 2097152);
  short* vTb = (short*)(wsb + 3 * SZ + 2097152);
  short* yat = (short*)(wsb + 4 * SZ + 2097152 + 4096);

  prep_kernel<<<dim3(4096), dim3(256), 0, stream>>>(x, Wq, Wk, Wv, Wo, xb, WT);
  qkv_kernel<<<dim3(96, 12), dim3(256), 0, stream>>>(xb, WT, qb, kb, vTb);
  attn_kernel<<<dim3(1536), dim3(256), 0, stream>>>(qb, kb, vTb, relT, relP, yat);
  proj_kernel<<<dim3(96, 4), dim3(256), 0, stream>>>(yat, WT, (float*)d_out);
}

// Round 6
// 215.253 us; speedup vs baseline: 1.2526x; 1.2526x over previous
//
#include <hip/hip_runtime.h>
#include <hip/hip_bf16.h>
#include <math.h>

#define B_  16
#define N_  16
#define T_  48
#define C_  512
#define H_  8
#define HD_ 64
#define L_  768
#define BL_ 12288

typedef __attribute__((ext_vector_type(8))) short b16x8;
typedef __attribute__((ext_vector_type(4))) float f32x4;
typedef __attribute__((ext_vector_type(2))) unsigned int u32x2;

__device__ __forceinline__ short f2b(float f) {
  __hip_bfloat16 h = __float2bfloat16(f);
  return *reinterpret_cast<short*>(&h);
}
// packed f32x2 -> bf16x2 (RNE), single VALU op
__device__ __forceinline__ unsigned cvt_pk_bf16(float a, float b) {
  unsigned d;
  asm("v_cvt_pk_bf16_f32 %0, %1, %2" : "=v"(d) : "v"(a), "v"(b));
  return d;
}
// 2^x, single transcendental VALU op (biases/scales pre-folded by log2e)
__device__ __forceinline__ float ex2(float x) {
  float d;
  asm("v_exp_f32 %0, %1" : "=v"(d) : "v"(x));
  return d;
}

// ---------------------------------------------------------------------------
// prep: blocks [0,3072) cast x fp32->bf16; blocks [3072,4096) cast+transpose
// weights into WT[mat][n][k] (Wq pre-scaled by log2(e)/8 for exp2 softmax).
// ---------------------------------------------------------------------------
__global__ __launch_bounds__(256) void prep_kernel(
    const float* __restrict__ x,
    const float* __restrict__ Wq, const float* __restrict__ Wk,
    const float* __restrict__ Wv, const float* __restrict__ Wo,
    short* __restrict__ xb, short* __restrict__ WT)
{
  __shared__ float tile[32][33];
  int blk = blockIdx.x;
  int tid = threadIdx.x;
  if (blk < 3072) {
    int i = blk * 256 + tid;
    const float4* src = (const float4*)(x + (size_t)i * 8);
    float4 a = src[0], b = src[1];
    short tmp[8] = {f2b(a.x), f2b(a.y), f2b(a.z), f2b(a.w),
                    f2b(b.x), f2b(b.y), f2b(b.z), f2b(b.w)};
    *(b16x8*)(xb + (size_t)i * 8) = *(b16x8*)tmp;
  } else {
    int idx = blk - 3072;
    int mat = idx >> 8, rem = idx & 255;
    const float* W = (mat == 0) ? Wq : (mat == 1) ? Wk : (mat == 2) ? Wv : Wo;
    float scale = (mat == 0) ? 0.18033688f : 1.0f;   // log2(e)/8
    int k0 = (rem >> 4) * 32, n0 = (rem & 15) * 32;
    int tx = tid & 31, ty = tid >> 5;
    for (int i = ty; i < 32; i += 8) tile[i][tx] = W[(size_t)(k0 + i) * 512 + n0 + tx];
    __syncthreads();
    short* dst = WT + (size_t)mat * 262144;
    for (int i = ty; i < 32; i += 8)
      dst[(size_t)(n0 + i) * 512 + k0 + tx] = f2b(tile[tx][i] * scale);
  }
}

// ---------------------------------------------------------------------------
// QKV GEMM, time-major permuted M-rows (rr = pt*16+pn) + LDS-staged epilogue.
//   q2,k2: [b][h][t][n][d]   vT2: [b][h][d][t][n]
// ---------------------------------------------------------------------------
__global__ __launch_bounds__(256) void qkv_kernel(
    const short* __restrict__ xb, const short* __restrict__ WT,
    short* __restrict__ q2, short* __restrict__ k2, short* __restrict__ vT2)
{
  __shared__ short smem[8192];              // As/Bs during K-loop; Ls in epilogue
  short (*As)[32] = (short(*)[32])smem;
  short (*Bs)[32] = (short(*)[32])(smem + 4096);
  int tid = threadIdx.x;
  int w = tid >> 6, lane = tid & 63, n16 = lane & 15, quad = lane >> 4;
  int bm = blockIdx.x, bn = blockIdx.y;
  int mat = bn >> 2;
  int ncol0 = (bn & 3) * 128;
  const short* Wt = WT + (size_t)mat * 262144;
  int bq = bm / 6;
  int rr0 = (bm % 6) * 128;

  f32x4 zero4 = {0.f, 0.f, 0.f, 0.f};
  f32x4 acc[4][4];
  #pragma unroll
  for (int mt = 0; mt < 4; ++mt)
    #pragma unroll
    for (int nt = 0; nt < 4; ++nt) acc[mt][nt] = zero4;

  int srow = tid >> 1, sch = (tid & 1) * 16;
  int rr = rr0 + srow;
  int pt = rr >> 4, pn = rr & 15;           // permuted row -> l = pn*48+pt
  const short* ga = xb + ((size_t)bq * 768 + pn * 48 + pt) * 512 + sch;
  const short* gb = Wt + (size_t)(ncol0 + srow) * 512 + sch;
  int wm = (w >> 1) * 64, wn = (w & 1) * 64;

  for (int kt = 0; kt < 16; ++kt) {
    b16x8 a0 = *(const b16x8*)(ga);
    b16x8 a1 = *(const b16x8*)(ga + 8);
    b16x8 b0 = *(const b16x8*)(gb);
    b16x8 b1 = *(const b16x8*)(gb + 8);
    ga += 32; gb += 32;
    __syncthreads();
    *(b16x8*)&As[srow][sch]     = a0;
    *(b16x8*)&As[srow][sch + 8] = a1;
    *(b16x8*)&Bs[srow][sch]     = b0;
    *(b16x8*)&Bs[srow][sch + 8] = b1;
    __syncthreads();
    b16x8 af[4], bf[4];
    #pragma unroll
    for (int mt = 0; mt < 4; ++mt) af[mt] = *(const b16x8*)&As[wm + mt * 16 + n16][quad * 8];
    #pragma unroll
    for (int nt = 0; nt < 4; ++nt) bf[nt] = *(const b16x8*)&Bs[wn + nt * 16 + n16][quad * 8];
    #pragma unroll
    for (int mt = 0; mt < 4; ++mt)
      #pragma unroll
      for (int nt = 0; nt < 4; ++nt)
        acc[mt][nt] = __builtin_amdgcn_mfma_f32_16x16x32_bf16(af[mt], bf[nt], acc[mt][nt], 0, 0, 0);
  }

  // epilogue: 4 chunks of 32 tile-rows staged through LDS, vector stores out
  short (*Ls)[136] = (short(*)[136])smem;   // 32 x 136 (pad: aligned, spread banks)
  for (int c = 0; c < 4; ++c) {
    __syncthreads();
    if ((w >> 1) == (c >> 1)) {             // waves owning rows 32c..32c+31
      int mtb = (c & 1) * 2;
      #pragma unroll
      for (int mi = 0; mi < 2; ++mi) {
        #pragma unroll
        for (int nt = 0; nt < 4; ++nt)
          #pragma unroll
          for (int r = 0; r < 4; ++r)
            Ls[mi * 16 + quad * 4 + r][wn + nt * 16 + n16] = f2b(acc[mtb + mi][nt][r]);
      }
    }
    __syncthreads();
    int rrc = rr0 + c * 32;
    if (mat != 2) {
      short* dst = (mat == 0) ? q2 : k2;
      int row = tid >> 3, c0 = (tid & 7) * 16;
      int hhg = (ncol0 + c0) >> 6, d0 = (ncol0 + c0) & 63;
      short* dp = dst + ((size_t)(bq * 8 + hhg) * 768 + rrc + row) * 64 + d0;
      *(b16x8*)dp       = *(b16x8*)&Ls[row][c0];
      *(b16x8*)(dp + 8) = *(b16x8*)&Ls[row][c0 + 8];
    } else {
      int cp = tid & 63, r8 = (tid >> 6) * 8;
      int c0 = 2 * cp;
      int hhg = (ncol0 + c0) >> 6, d0 = (ncol0 + c0) & 63;
      short t0[8], t1[8];
      #pragma unroll
      for (int j = 0; j < 8; ++j) { t0[j] = Ls[r8 + j][c0]; t1[j] = Ls[r8 + j][c0 + 1]; }
      short* dp = vT2 + ((size_t)(bq * 8 + hhg) * 64 + d0) * 768 + rrc + r8;
      *(b16x8*)dp         = *(b16x8*)t0;
      *(b16x8*)(dp + 768) = *(b16x8*)t1;
    }
  }
}

// ---------------------------------------------------------------------------
// Attention (R10 core): key-parity split (4 waves/block = 2 q-pairs x 2 key
// halves, no-max softmax => LDS add-merge) with SINGLE-BUFFERED K/V.
// R9's explicit double-buffer (64 regs) pushed wave state to ~135 > the
// (256,4) budget of 128 -> spill (158 MB scratch writes). Single buffer:
// q16 + K16 + V16 + O32 + misc ~25 = ~105 regs, fits with headroom.
// V is consumed ~300cy after issue (hidden); K's exposed L2 latency is
// covered by 4 waves/SIMD TLP + compiler hoisting into the ~20 spare regs.
// ---------------------------------------------------------------------------
__global__ __launch_bounds__(256, 4) void attn_kernel(
    const short* __restrict__ q2, const short* __restrict__ k2,
    const short* __restrict__ vT2,
    const float* __restrict__ relT, const float* __restrict__ relP,
    short* __restrict__ yatt)
{
  __shared__ float btL[2][96];
  __shared__ float mO[2][8][4][64];         // [pair][acc][r][lane] partial O
  __shared__ float mS[2][2][64];            // [pair][A/B][lane] partial ps

  const float LOG2E = 1.44269504f;
  int tid = threadIdx.x;
  int wv2 = tid >> 6, lane = tid & 63, n16 = lane & 15, quad = lane >> 4;
  int p  = wv2 & 1;                         // pair-in-block
  int kh = wv2 >> 1;                        // key-parity half (0=even kt2, 1=odd)
  int blk = blockIdx.x;
  int h = blk & 7;                          // XCD-locality
  int g = blk >> 3;
  int pg = g % 12, b = g / 12;
  int pair = pg * 2 + p;
  int qtA = pair, qtB = 47 - pair;
  int nA = (qtA + 2) >> 1, nB = (qtB + 2) >> 1;

  if (wv2 < 2) {
    btL[wv2][lane] = relT[(lane < 95 ? lane : 94) * 8 + h] * LOG2E;
    if (lane < 32)
      btL[wv2][64 + lane] = relT[((64 + lane) < 95 ? 64 + lane : 94) * 8 + h] * LOG2E;
  }
  __syncthreads();

  // swapped layout: reg r = key particle quad*4+r, lane n16 = q particle
  // bias_p[q][k] = relP[k - q + 15]
  float bpT[4];
  #pragma unroll
  for (int r = 0; r < 4; ++r)
    bpT[r] = relP[(quad * 4 + r - n16 + 15) * 8 + h] * LOG2E;

  size_t bh = (size_t)(b * 8 + h);
  const short* qb = q2 + bh * 49152;
  const short* kb = k2 + bh * 49152;
  const short* vb = vT2 + bh * 49152;

  b16x8 qA0 = *(const b16x8*)(qb + (qtA * 16 + n16) * 64 + quad * 8);
  b16x8 qA1 = *(const b16x8*)(qb + (qtA * 16 + n16) * 64 + quad * 8 + 32);
  b16x8 qB0 = *(const b16x8*)(qb + (qtB * 16 + n16) * 64 + quad * 8);
  b16x8 qB1 = *(const b16x8*)(qb + (qtB * 16 + n16) * 64 + quad * 8 + 32);

  f32x4 zero4 = {0.f, 0.f, 0.f, 0.f};
  f32x4 oA[4], oB[4];
  float psA = 0.f, psB = 0.f;
  #pragma unroll
  for (int nt = 0; nt < 4; ++nt) { oA[nt] = zero4; oB[nt] = zero4; }

  // exp2 + bias on S^T tile pair, pack to the PV A-fragment in-register.
  auto exp_pack = [&](const f32x4& s0, const f32x4& s1, float bt0, float bt1,
                      float& ps) -> b16x8 {
    float e00 = ex2(s0[0] + bt0 + bpT[0]);
    float e01 = ex2(s0[1] + bt0 + bpT[1]);
    float e02 = ex2(s0[2] + bt0 + bpT[2]);
    float e03 = ex2(s0[3] + bt0 + bpT[3]);
    float e10 = ex2(s1[0] + bt1 + bpT[0]);
    float e11 = ex2(s1[1] + bt1 + bpT[1]);
    float e12 = ex2(s1[2] + bt1 + bpT[2]);
    float e13 = ex2(s1[3] + bt1 + bpT[3]);
    ps += ((e00 + e01) + (e02 + e03)) + ((e10 + e11) + (e12 + e13));
    unsigned p0 = cvt_pk_bf16(e00, e01);
    unsigned p1 = cvt_pk_bf16(e02, e03);
    unsigned p2 = cvt_pk_bf16(e10, e11);
    unsigned p3 = cvt_pk_bf16(e12, e13);
    u32x2 a02 = __builtin_amdgcn_permlane32_swap(p0, p2, false, false);
    u32x2 z02 = __builtin_amdgcn_permlane16_swap(a02.x, a02.y, false, false);
    u32x2 a13 = __builtin_amdgcn_permlane32_swap(p1, p3, false, false);
    u32x2 z13 = __builtin_amdgcn_permlane16_swap(a13.x, a13.y, false, false);
    union { unsigned u[4]; b16x8 v; } r;
    r.u[0] = z02.x;
    r.u[1] = z13.x;
    r.u[2] = z02.y;
    r.u[3] = z13.y;
    return r.v;
  };

  // key-parity split, single-buffered: this wave handles kt2 = kh, kh+2, ...
  for (int kt2 = kh; kt2 < nB; kt2 += 2) {
    // K fragments (consumed immediately; latency covered by TLP)
    const short* kp = kb + (size_t)(kt2 * 32 + n16) * 64 + quad * 8;
    b16x8 k0 = *(const b16x8*)kp;
    b16x8 k1 = *(const b16x8*)(kp + 32);
    b16x8 k2f = *(const b16x8*)(kp + 1024);
    b16x8 k3 = *(const b16x8*)(kp + 1024 + 32);
    // V fragments issued now, consumed ~300cy later (after QK+exp+pack)
    const short* vp = vb + (size_t)n16 * 768 + kt2 * 32 + quad * 8;
    b16x8 v0 = *(const b16x8*)vp;
    b16x8 v1 = *(const b16x8*)(vp + 16 * 768);
    b16x8 v2 = *(const b16x8*)(vp + 32 * 768);
    b16x8 v3 = *(const b16x8*)(vp + 48 * 768);

    int kt0 = kt2 * 2;
    bool doA = kt2 < nA;                    // wave-uniform
    f32x4 sB0 = zero4, sB1 = zero4;
    sB0 = __builtin_amdgcn_mfma_f32_16x16x32_bf16(k0, qB0, sB0, 0, 0, 0);
    sB0 = __builtin_amdgcn_mfma_f32_16x16x32_bf16(k1, qB1, sB0, 0, 0, 0);
    sB1 = __builtin_amdgcn_mfma_f32_16x16x32_bf16(k2f, qB0, sB1, 0, 0, 0);
    sB1 = __builtin_amdgcn_mfma_f32_16x16x32_bf16(k3, qB1, sB1, 0, 0, 0);
    f32x4 sA0 = zero4, sA1 = zero4;
    if (doA) {
      sA0 = __builtin_amdgcn_mfma_f32_16x16x32_bf16(k0, qA0, sA0, 0, 0, 0);
      sA0 = __builtin_amdgcn_mfma_f32_16x16x32_bf16(k1, qA1, sA0, 0, 0, 0);
      sA1 = __builtin_amdgcn_mfma_f32_16x16x32_bf16(k2f, qA0, sA1, 0, 0, 0);
      sA1 = __builtin_amdgcn_mfma_f32_16x16x32_bf16(k3, qA1, sA1, 0, 0, 0);
    }
    float btB0 = (kt0 <= qtB) ? btL[p][kt0 - qtB + 47] : -1e30f;
    float btB1 = (kt0 + 1 <= qtB) ? btL[p][kt0 + 1 - qtB + 47] : -1e30f;
    b16x8 pfB = exp_pack(sB0, sB1, btB0, btB1, psB);
    oB[0] = __builtin_amdgcn_mfma_f32_16x16x32_bf16(pfB, v0, oB[0], 0, 0, 0);
    oB[1] = __builtin_amdgcn_mfma_f32_16x16x32_bf16(pfB, v1, oB[1], 0, 0, 0);
    oB[2] = __builtin_amdgcn_mfma_f32_16x16x32_bf16(pfB, v2, oB[2], 0, 0, 0);
    oB[3] = __builtin_amdgcn_mfma_f32_16x16x32_bf16(pfB, v3, oB[3], 0, 0, 0);
    if (doA) {
      float btA0 = (kt0 <= qtA) ? btL[p][kt0 - qtA + 47] : -1e30f;
      float btA1 = (kt0 + 1 <= qtA) ? btL[p][kt0 + 1 - qtA + 47] : -1e30f;
      b16x8 pfA = exp_pack(sA0, sA1, btA0, btA1, psA);
      oA[0] = __builtin_amdgcn_mfma_f32_16x16x32_bf16(pfA, v0, oA[0], 0, 0, 0);
      oA[1] = __builtin_amdgcn_mfma_f32_16x16x32_bf16(pfA, v1, oA[1], 0, 0, 0);
      oA[2] = __builtin_amdgcn_mfma_f32_16x16x32_bf16(pfA, v2, oA[2], 0, 0, 0);
      oA[3] = __builtin_amdgcn_mfma_f32_16x16x32_bf16(pfA, v3, oA[3], 0, 0, 0);
    }
  }

  // merge the two key-halves through LDS (pure add: no-max softmax)
  if (kh == 1) {
    #pragma unroll
    for (int nt = 0; nt < 4; ++nt)
      #pragma unroll
      for (int r = 0; r < 4; ++r) {
        mO[p][nt][r][lane]     = oA[nt][r];
        mO[p][nt + 4][r][lane] = oB[nt][r];
      }
    mS[p][0][lane] = psA;
    mS[p][1][lane] = psB;
  }
  __syncthreads();
  if (kh == 1) return;
  #pragma unroll
  for (int nt = 0; nt < 4; ++nt)
    #pragma unroll
    for (int r = 0; r < 4; ++r) {
      oA[nt][r] += mO[p][nt][r][lane];
      oB[nt][r] += mO[p][nt + 4][r][lane];
    }
  psA += mS[p][0][lane];
  psB += mS[p][1][lane];

  // denom: per-lane partial (q = n16, keys split across quads) -> full sum
  psA += __shfl_xor(psA, 16); psA += __shfl_xor(psA, 32);
  psB += __shfl_xor(psB, 16); psB += __shfl_xor(psB, 32);
  float invA = 1.0f / psA, invB = 1.0f / psB;
  // redistribute to C-layout rows: lane needs 1/ps for q = quad*4+r
  float pnA[4], pnB[4];
  #pragma unroll
  for (int r = 0; r < 4; ++r) {
    pnA[r] = __shfl(invA, quad * 4 + r);
    pnB[r] = __shfl(invB, quad * 4 + r);
  }

  #pragma unroll
  for (int nt = 0; nt < 4; ++nt) {
    int c = h * 64 + nt * 16 + n16;
    #pragma unroll
    for (int r = 0; r < 4; ++r) {
      int qn = quad * 4 + r;
      yatt[((size_t)b * 768 + qn * 48 + qtA) * 512 + c] = f2b(oA[nt][r] * pnA[r]);
      yatt[((size_t)b * 768 + qn * 48 + qtB) * 512 + c] = f2b(oB[nt][r] * pnB[r]);
    }
  }
}

// ---------------------------------------------------------------------------
// proj: yatt(12288x512,bf16) @ WoT -> out fp32
// ---------------------------------------------------------------------------
__global__ __launch_bounds__(256) void proj_kernel(
    const short* __restrict__ yatt, const short* __restrict__ WT,
    float* __restrict__ out)
{
  __shared__ short As[128][32];
  __shared__ short Bs[128][32];
  int tid = threadIdx.x;
  int w = tid >> 6, lane = tid & 63, n16 = lane & 15, quad = lane >> 4;
  int row0 = blockIdx.x * 128;
  int ncol0 = blockIdx.y * 128;
  const short* Wt = WT + (size_t)3 * 262144;

  f32x4 zero4 = {0.f, 0.f, 0.f, 0.f};
  f32x4 acc[4][4];
  #pragma unroll
  for (int mt = 0; mt < 4; ++mt)
    #pragma unroll
    for (int nt = 0; nt < 4; ++nt) acc[mt][nt] = zero4;

  int srow = tid >> 1, sch = (tid & 1) * 16;
  const short* ga = yatt + (size_t)(row0 + srow) * 512 + sch;
  const short* gb = Wt + (size_t)(ncol0 + srow) * 512 + sch;
  int wm = (w >> 1) * 64, wn = (w & 1) * 64;

  for (int kt = 0; kt < 16; ++kt) {
    b16x8 a0 = *(const b16x8*)(ga);
    b16x8 a1 = *(const b16x8*)(ga + 8);
    b16x8 b0 = *(const b16x8*)(gb);
    b16x8 b1 = *(const b16x8*)(gb + 8);
    ga += 32; gb += 32;
    __syncthreads();
    *(b16x8*)&As[srow][sch]     = a0;
    *(b16x8*)&As[srow][sch + 8] = a1;
    *(b16x8*)&Bs[srow][sch]     = b0;
    *(b16x8*)&Bs[srow][sch + 8] = b1;
    __syncthreads();
    b16x8 af[4], bf[4];
    #pragma unroll
    for (int mt = 0; mt < 4; ++mt) af[mt] = *(const b16x8*)&As[wm + mt * 16 + n16][quad * 8];
    #pragma unroll
    for (int nt = 0; nt < 4; ++nt) bf[nt] = *(const b16x8*)&Bs[wn + nt * 16 + n16][quad * 8];
    #pragma unroll
    for (int mt = 0; mt < 4; ++mt)
      #pragma unroll
      for (int nt = 0; nt < 4; ++nt)
        acc[mt][nt] = __builtin_amdgcn_mfma_f32_16x16x32_bf16(af[mt], bf[nt], acc[mt][nt], 0, 0, 0);
  }

  #pragma unroll
  for (int mt = 0; mt < 4; ++mt) {
    int rowb = row0 + wm + mt * 16 + quad * 4;
    #pragma unroll
    for (int nt = 0; nt < 4; ++nt) {
      int colg = ncol0 + wn + nt * 16 + n16;
      #pragma unroll
      for (int r = 0; r < 4; ++r)
        out[(size_t)(rowb + r) * 512 + colg] = acc[mt][nt][r];
    }
  }
}

// ---------------------------------------------------------------------------
extern "C" void kernel_launch(void* const* d_in, const int* in_sizes, int n_in,
                              void* d_out, int out_size, void* d_ws, size_t ws_size,
                              hipStream_t stream) {
  const float* x    = (const float*)d_in[0];
  const float* Wq   = (const float*)d_in[1];
  const float* Wk   = (const float*)d_in[2];
  const float* Wv   = (const float*)d_in[3];
  const float* Wo   = (const float*)d_in[4];
  const float* relT = (const float*)d_in[5];
  const float* relP = (const float*)d_in[6];

  char* wsb = (char*)d_ws;
  const size_t SZ = (size_t)BL_ * C_ * 2;
  short* xb  = (short*)(wsb);
  short* WT  = (short*)(wsb + SZ);
  short* qb  = (short*)(wsb + SZ + 2097152);
  short* kb  = (short*)(wsb + 2 * SZ + 2097152);
  short* vTb = (short*)(wsb + 3 * SZ + 2097152);
  short* yat = (short*)(wsb + 4 * SZ + 2097152 + 4096);

  prep_kernel<<<dim3(4096), dim3(256), 0, stream>>>(x, Wq, Wk, Wv, Wo, xb, WT);
  qkv_kernel<<<dim3(96, 12), dim3(256), 0, stream>>>(xb, WT, qb, kb, vTb);
  attn_kernel<<<dim3(1536), dim3(256), 0, stream>>>(qb, kb, vTb, relT, relP, yat);
  proj_kernel<<<dim3(96, 4), dim3(256), 0, stream>>>(yat, WT, (float*)d_out);
}

// Round 7
// 192.118 us; speedup vs baseline: 1.4034x; 1.1204x over previous
//
#include <hip/hip_runtime.h>
#include <hip/hip_bf16.h>
#include <math.h>

#define B_  16
#define N_  16
#define T_  48
#define C_  512
#define H_  8
#define HD_ 64
#define L_  768
#define BL_ 12288

typedef __attribute__((ext_vector_type(8))) short b16x8;
typedef __attribute__((ext_vector_type(4))) float f32x4;
typedef __attribute__((ext_vector_type(2))) unsigned int u32x2;

__device__ __forceinline__ short f2b(float f) {
  __hip_bfloat16 h = __float2bfloat16(f);
  return *reinterpret_cast<short*>(&h);
}
// packed f32x2 -> bf16x2 (RNE), single VALU op
__device__ __forceinline__ unsigned cvt_pk_bf16(float a, float b) {
  unsigned d;
  asm("v_cvt_pk_bf16_f32 %0, %1, %2" : "=v"(d) : "v"(a), "v"(b));
  return d;
}
// 2^x, single transcendental VALU op (biases/scales pre-folded by log2e)
__device__ __forceinline__ float ex2(float x) {
  float d;
  asm("v_exp_f32 %0, %1" : "=v"(d) : "v"(x));
  return d;
}
// async global->LDS, 16B per lane; dest must be linear base + lane*16
__device__ __forceinline__ void gload16(const void* g, void* l) {
  __builtin_amdgcn_global_load_lds(
      (const __attribute__((address_space(1))) void*)g,
      (__attribute__((address_space(3))) void*)l, 16, 0, 0);
}

// ---------------------------------------------------------------------------
// prep: blocks [0,3072) cast x fp32->bf16; blocks [3072,4096) cast+transpose
// weights into WT[mat][n][k] (Wq pre-scaled by log2(e)/8 for exp2 softmax).
// ---------------------------------------------------------------------------
__global__ __launch_bounds__(256) void prep_kernel(
    const float* __restrict__ x,
    const float* __restrict__ Wq, const float* __restrict__ Wk,
    const float* __restrict__ Wv, const float* __restrict__ Wo,
    short* __restrict__ xb, short* __restrict__ WT)
{
  __shared__ float tile[32][33];
  int blk = blockIdx.x;
  int tid = threadIdx.x;
  if (blk < 3072) {
    int i = blk * 256 + tid;
    const float4* src = (const float4*)(x + (size_t)i * 8);
    float4 a = src[0], b = src[1];
    short tmp[8] = {f2b(a.x), f2b(a.y), f2b(a.z), f2b(a.w),
                    f2b(b.x), f2b(b.y), f2b(b.z), f2b(b.w)};
    *(b16x8*)(xb + (size_t)i * 8) = *(b16x8*)tmp;
  } else {
    int idx = blk - 3072;
    int mat = idx >> 8, rem = idx & 255;
    const float* W = (mat == 0) ? Wq : (mat == 1) ? Wk : (mat == 2) ? Wv : Wo;
    float scale = (mat == 0) ? 0.18033688f : 1.0f;   // log2(e)/8
    int k0 = (rem >> 4) * 32, n0 = (rem & 15) * 32;
    int tx = tid & 31, ty = tid >> 5;
    for (int i = ty; i < 32; i += 8) tile[i][tx] = W[(size_t)(k0 + i) * 512 + n0 + tx];
    __syncthreads();
    short* dst = WT + (size_t)mat * 262144;
    for (int i = ty; i < 32; i += 8)
      dst[(size_t)(n0 + i) * 512 + k0 + tx] = f2b(tile[tx][i] * scale);
  }
}

// ---------------------------------------------------------------------------
// QKV GEMM (R11): global_load_lds width-16 double-buffered staging (the
// ladder's biggest single lever, m93->m97 +69%). Per K-step: issue next
// tile's 4 async loads, ds_read + 16 MFMA on current, ONE barrier (its
// built-in vmcnt(0) drain covers the loads). No reg round-trip, no
// ds_writes, one barrier instead of two.
//   q2,k2: [b][h][t][n][d]   vT2: [b][h][d][t][n]
// ---------------------------------------------------------------------------
__global__ __launch_bounds__(256) void qkv_kernel(
    const short* __restrict__ xb, const short* __restrict__ WT,
    short* __restrict__ q2, short* __restrict__ k2, short* __restrict__ vT2)
{
  __shared__ __align__(16) short smem[16384];  // 32KB: [buf][A 4096 | B 4096]
  int tid = threadIdx.x;
  int w = tid >> 6, lane = tid & 63, n16 = lane & 15, quad = lane >> 4;
  int bm = blockIdx.x, bn = blockIdx.y;
  int mat = bn >> 2;
  int ncol0 = (bn & 3) * 128;
  const short* Wt = WT + (size_t)mat * 262144;
  int bq = bm / 6;
  int rr0 = (bm % 6) * 128;

  f32x4 zero4 = {0.f, 0.f, 0.f, 0.f};
  f32x4 acc[4][4];
  #pragma unroll
  for (int mt = 0; mt < 4; ++mt)
    #pragma unroll
    for (int nt = 0; nt < 4; ++nt) acc[mt][nt] = zero4;

  // per-lane global row pointers for the 2 staging issues (16 rows each):
  // issue i covers rows (w+4i)*16 .. +15; lane l -> row +(l>>2), 16B chunk (l&3)
  const short* gA[2];
  const short* gB[2];
  #pragma unroll
  for (int i = 0; i < 2; ++i) {
    int r16 = w + 4 * i;
    int rr = rr0 + r16 * 16 + (lane >> 2);
    int pt = rr >> 4, pn = rr & 15;          // permuted row -> l = pn*48+pt
    gA[i] = xb + ((size_t)bq * 768 + pn * 48 + pt) * 512 + (lane & 3) * 8;
    gB[i] = Wt + (size_t)(ncol0 + r16 * 16 + (lane >> 2)) * 512 + (lane & 3) * 8;
  }
  int ldsoff = (w) * 512 + lane * 8;         // shorts, within a 4096-short tile

  auto stage = [&](int buf, int kt) {
    short* As = smem + buf * 8192;
    short* Bs = As + 4096;
    #pragma unroll
    for (int i = 0; i < 2; ++i) {
      gload16(gA[i] + kt * 32, As + i * 2048 + ldsoff);
      gload16(gB[i] + kt * 32, Bs + i * 2048 + ldsoff);
    }
  };

  int wm = (w >> 1) * 64, wn = (w & 1) * 64;
  stage(0, 0);
  __syncthreads();                           // vmcnt(0) drain + barrier
  int buf = 0;
  for (int kt = 0; kt < 16; ++kt) {
    if (kt < 15) stage(buf ^ 1, kt + 1);
    const short (*As)[32] = (const short(*)[32])(smem + buf * 8192);
    const short (*Bs)[32] = (const short(*)[32])(smem + buf * 8192 + 4096);
    b16x8 af[4], bf[4];
    #pragma unroll
    for (int mt = 0; mt < 4; ++mt) af[mt] = *(const b16x8*)&As[wm + mt * 16 + n16][quad * 8];
    #pragma unroll
    for (int nt = 0; nt < 4; ++nt) bf[nt] = *(const b16x8*)&Bs[wn + nt * 16 + n16][quad * 8];
    #pragma unroll
    for (int mt = 0; mt < 4; ++mt)
      #pragma unroll
      for (int nt = 0; nt < 4; ++nt)
        acc[mt][nt] = __builtin_amdgcn_mfma_f32_16x16x32_bf16(af[mt], bf[nt], acc[mt][nt], 0, 0, 0);
    __syncthreads();                         // waves done reading + next tile landed
    buf ^= 1;
  }

  // epilogue: 4 chunks of 32 tile-rows staged through LDS, vector stores out
  short (*Ls)[136] = (short(*)[136])smem;    // 32 x 136 (pad: aligned, spread banks)
  for (int c = 0; c < 4; ++c) {
    __syncthreads();
    if ((w >> 1) == (c >> 1)) {              // waves owning rows 32c..32c+31
      int mtb = (c & 1) * 2;
      #pragma unroll
      for (int mi = 0; mi < 2; ++mi) {
        #pragma unroll
        for (int nt = 0; nt < 4; ++nt)
          #pragma unroll
          for (int r = 0; r < 4; ++r)
            Ls[mi * 16 + quad * 4 + r][wn + nt * 16 + n16] = f2b(acc[mtb + mi][nt][r]);
      }
    }
    __syncthreads();
    int rrc = rr0 + c * 32;
    if (mat != 2) {
      short* dst = (mat == 0) ? q2 : k2;
      int row = tid >> 3, c0 = (tid & 7) * 16;
      int hhg = (ncol0 + c0) >> 6, d0 = (ncol0 + c0) & 63;
      short* dp = dst + ((size_t)(bq * 8 + hhg) * 768 + rrc + row) * 64 + d0;
      *(b16x8*)dp       = *(b16x8*)&Ls[row][c0];
      *(b16x8*)(dp + 8) = *(b16x8*)&Ls[row][c0 + 8];
    } else {
      int cp = tid & 63, r8 = (tid >> 6) * 8;
      int c0 = 2 * cp;
      int hhg = (ncol0 + c0) >> 6, d0 = (ncol0 + c0) & 63;
      short t0[8], t1[8];
      #pragma unroll
      for (int j = 0; j < 8; ++j) { t0[j] = Ls[r8 + j][c0]; t1[j] = Ls[r8 + j][c0 + 1]; }
      short* dp = vT2 + ((size_t)(bq * 8 + hhg) * 64 + d0) * 768 + rrc + r8;
      *(b16x8*)dp         = *(b16x8*)t0;
      *(b16x8*)(dp + 768) = *(b16x8*)t1;
    }
  }
}

// ---------------------------------------------------------------------------
// Attention (R11 = R6 revert + exp2): swapped QK^T in-register softmax,
// 2 bands/wave, K/V prefetch double-buffer — the measured 65 µs optimum.
// Key-split variants (R8/R10) measured slower: dbuf ILP > extra TLP.
// ---------------------------------------------------------------------------
__global__ __launch_bounds__(128, 3) void attn_kernel(
    const short* __restrict__ q2, const short* __restrict__ k2,
    const short* __restrict__ vT2,
    const float* __restrict__ relT, const float* __restrict__ relP,
    short* __restrict__ yatt)
{
  __shared__ float btL[2][96];

  const float LOG2E = 1.44269504f;
  int tid = threadIdx.x;
  int wv = tid >> 6, lane = tid & 63, n16 = lane & 15, quad = lane >> 4;
  int blk = blockIdx.x;
  int h = blk & 7;                          // XCD-locality
  int g = blk >> 3;
  int pg = g % 12, b = g / 12;
  int pair = pg * 2 + wv;
  int qtA = pair, qtB = 47 - pair;
  int nA = (qtA + 2) >> 1, nB = (qtB + 2) >> 1;

  btL[wv][lane] = relT[(lane < 95 ? lane : 94) * 8 + h] * LOG2E;
  if (lane < 32) btL[wv][64 + lane] = relT[((64 + lane) < 95 ? 64 + lane : 94) * 8 + h] * LOG2E;

  // swapped layout: reg r = key particle quad*4+r, lane n16 = q particle
  // bias_p[q][k] = relP[k - q + 15]
  float bpT[4];
  #pragma unroll
  for (int r = 0; r < 4; ++r)
    bpT[r] = relP[(quad * 4 + r - n16 + 15) * 8 + h] * LOG2E;

  size_t bh = (size_t)(b * 8 + h);
  const short* qb = q2 + bh * 49152;
  const short* kb = k2 + bh * 49152;
  const short* vb = vT2 + bh * 49152;

  b16x8 qA0 = *(const b16x8*)(qb + (qtA * 16 + n16) * 64 + quad * 8);
  b16x8 qA1 = *(const b16x8*)(qb + (qtA * 16 + n16) * 64 + quad * 8 + 32);
  b16x8 qB0 = *(const b16x8*)(qb + (qtB * 16 + n16) * 64 + quad * 8);
  b16x8 qB1 = *(const b16x8*)(qb + (qtB * 16 + n16) * 64 + quad * 8 + 32);

  f32x4 zero4 = {0.f, 0.f, 0.f, 0.f};
  f32x4 oA[4], oB[4];
  float psA = 0.f, psB = 0.f;
  #pragma unroll
  for (int nt = 0; nt < 4; ++nt) { oA[nt] = zero4; oB[nt] = zero4; }

  b16x8 kfa[4], kfb[4], vfa[4], vfb[4];
  auto loadKV = [&](int kt2, b16x8* kf, b16x8* vf) {
    const short* kp = kb + (size_t)(kt2 * 32 + n16) * 64 + quad * 8;
    kf[0] = *(const b16x8*)kp;
    kf[1] = *(const b16x8*)(kp + 32);
    kf[2] = *(const b16x8*)(kp + 1024);
    kf[3] = *(const b16x8*)(kp + 1024 + 32);
    const short* vp = vb + (size_t)n16 * 768 + kt2 * 32 + quad * 8;
    vf[0] = *(const b16x8*)vp;
    vf[1] = *(const b16x8*)(vp + 16 * 768);
    vf[2] = *(const b16x8*)(vp + 32 * 768);
    vf[3] = *(const b16x8*)(vp + 48 * 768);
  };

  // exp2+bias on S^T tile pair, pack to the PV A-fragment in-register.
  auto exp_pack = [&](const f32x4& s0, const f32x4& s1, float bt0, float bt1,
                      float& ps) -> b16x8 {
    float e00 = ex2(s0[0] + bt0 + bpT[0]);
    float e01 = ex2(s0[1] + bt0 + bpT[1]);
    float e02 = ex2(s0[2] + bt0 + bpT[2]);
    float e03 = ex2(s0[3] + bt0 + bpT[3]);
    float e10 = ex2(s1[0] + bt1 + bpT[0]);
    float e11 = ex2(s1[1] + bt1 + bpT[1]);
    float e12 = ex2(s1[2] + bt1 + bpT[2]);
    float e13 = ex2(s1[3] + bt1 + bpT[3]);
    ps += ((e00 + e01) + (e02 + e03)) + ((e10 + e11) + (e12 + e13));
    unsigned p0 = cvt_pk_bf16(e00, e01);
    unsigned p1 = cvt_pk_bf16(e02, e03);
    unsigned p2 = cvt_pk_bf16(e10, e11);
    unsigned p3 = cvt_pk_bf16(e12, e13);
    u32x2 a02 = __builtin_amdgcn_permlane32_swap(p0, p2, false, false);
    u32x2 z02 = __builtin_amdgcn_permlane16_swap(a02.x, a02.y, false, false);
    u32x2 a13 = __builtin_amdgcn_permlane32_swap(p1, p3, false, false);
    u32x2 z13 = __builtin_amdgcn_permlane16_swap(a13.x, a13.y, false, false);
    union { unsigned u[4]; b16x8 v; } r;
    r.u[0] = z02.x;
    r.u[1] = z13.x;
    r.u[2] = z02.y;
    r.u[3] = z13.y;
    return r.v;
  };

  auto step = [&](int kt2, const b16x8* kf, const b16x8* vf) {
    int kt0 = kt2 * 2;
    bool doA = kt2 < nA;                    // wave-uniform
    f32x4 sB0 = zero4, sB1 = zero4;
    sB0 = __builtin_amdgcn_mfma_f32_16x16x32_bf16(kf[0], qB0, sB0, 0, 0, 0);
    sB0 = __builtin_amdgcn_mfma_f32_16x16x32_bf16(kf[1], qB1, sB0, 0, 0, 0);
    sB1 = __builtin_amdgcn_mfma_f32_16x16x32_bf16(kf[2], qB0, sB1, 0, 0, 0);
    sB1 = __builtin_amdgcn_mfma_f32_16x16x32_bf16(kf[3], qB1, sB1, 0, 0, 0);
    f32x4 sA0 = zero4, sA1 = zero4;
    if (doA) {
      sA0 = __builtin_amdgcn_mfma_f32_16x16x32_bf16(kf[0], qA0, sA0, 0, 0, 0);
      sA0 = __builtin_amdgcn_mfma_f32_16x16x32_bf16(kf[1], qA1, sA0, 0, 0, 0);
      sA1 = __builtin_amdgcn_mfma_f32_16x16x32_bf16(kf[2], qA0, sA1, 0, 0, 0);
      sA1 = __builtin_amdgcn_mfma_f32_16x16x32_bf16(kf[3], qA1, sA1, 0, 0, 0);
    }
    float btB0 = (kt0 <= qtB) ? btL[wv][kt0 - qtB + 47] : -1e30f;
    float btB1 = (kt0 + 1 <= qtB) ? btL[wv][kt0 + 1 - qtB + 47] : -1e30f;
    b16x8 pfB = exp_pack(sB0, sB1, btB0, btB1, psB);
    #pragma unroll
    for (int nt = 0; nt < 4; ++nt)
      oB[nt] = __builtin_amdgcn_mfma_f32_16x16x32_bf16(pfB, vf[nt], oB[nt], 0, 0, 0);
    if (doA) {
      float btA0 = (kt0 <= qtA) ? btL[wv][kt0 - qtA + 47] : -1e30f;
      float btA1 = (kt0 + 1 <= qtA) ? btL[wv][kt0 + 1 - qtA + 47] : -1e30f;
      b16x8 pfA = exp_pack(sA0, sA1, btA0, btA1, psA);
      #pragma unroll
      for (int nt = 0; nt < 4; ++nt)
        oA[nt] = __builtin_amdgcn_mfma_f32_16x16x32_bf16(pfA, vf[nt], oA[nt], 0, 0, 0);
    }
  };

  loadKV(0, kfa, vfa);
  for (int kt2 = 0; kt2 < nB; kt2 += 2) {
    if (kt2 + 1 < nB) loadKV(kt2 + 1, kfb, vfb);
    step(kt2, kfa, vfa);
    if (kt2 + 1 < nB) {
      if (kt2 + 2 < nB) loadKV(kt2 + 2, kfa, vfa);
      step(kt2 + 1, kfb, vfb);
    }
  }

  // denom: per-lane partial (q = n16, keys split across quads) -> full sum
  psA += __shfl_xor(psA, 16); psA += __shfl_xor(psA, 32);
  psB += __shfl_xor(psB, 16); psB += __shfl_xor(psB, 32);
  float invA = 1.0f / psA, invB = 1.0f / psB;
  // redistribute to C-layout rows: lane needs 1/ps for q = quad*4+r
  float pnA[4], pnB[4];
  #pragma unroll
  for (int r = 0; r < 4; ++r) {
    pnA[r] = __shfl(invA, quad * 4 + r);
    pnB[r] = __shfl(invB, quad * 4 + r);
  }

  #pragma unroll
  for (int nt = 0; nt < 4; ++nt) {
    int c = h * 64 + nt * 16 + n16;
    #pragma unroll
    for (int r = 0; r < 4; ++r) {
      int qn = quad * 4 + r;
      yatt[((size_t)b * 768 + qn * 48 + qtA) * 512 + c] = f2b(oA[nt][r] * pnA[r]);
      yatt[((size_t)b * 768 + qn * 48 + qtB) * 512 + c] = f2b(oB[nt][r] * pnB[r]);
    }
  }
}

// ---------------------------------------------------------------------------
// proj (R11): yatt(12288x512,bf16) @ WoT -> out fp32, same global_load_lds
// 2-phase staging as qkv.
// ---------------------------------------------------------------------------
__global__ __launch_bounds__(256) void proj_kernel(
    const short* __restrict__ yatt, const short* __restrict__ WT,
    float* __restrict__ out)
{
  __shared__ __align__(16) short smem[16384];  // 32KB double buffer
  int tid = threadIdx.x;
  int w = tid >> 6, lane = tid & 63, n16 = lane & 15, quad = lane >> 4;
  int row0 = blockIdx.x * 128;
  int ncol0 = blockIdx.y * 128;
  const short* Wt = WT + (size_t)3 * 262144;

  f32x4 zero4 = {0.f, 0.f, 0.f, 0.f};
  f32x4 acc[4][4];
  #pragma unroll
  for (int mt = 0; mt < 4; ++mt)
    #pragma unroll
    for (int nt = 0; nt < 4; ++nt) acc[mt][nt] = zero4;

  const short* gA[2];
  const short* gB[2];
  #pragma unroll
  for (int i = 0; i < 2; ++i) {
    int r16 = w + 4 * i;
    gA[i] = yatt + (size_t)(row0 + r16 * 16 + (lane >> 2)) * 512 + (lane & 3) * 8;
    gB[i] = Wt + (size_t)(ncol0 + r16 * 16 + (lane >> 2)) * 512 + (lane & 3) * 8;
  }
  int ldsoff = w * 512 + lane * 8;

  auto stage = [&](int buf, int kt) {
    short* As = smem + buf * 8192;
    short* Bs = As + 4096;
    #pragma unroll
    for (int i = 0; i < 2; ++i) {
      gload16(gA[i] + kt * 32, As + i * 2048 + ldsoff);
      gload16(gB[i] + kt * 32, Bs + i * 2048 + ldsoff);
    }
  };

  int wm = (w >> 1) * 64, wn = (w & 1) * 64;
  stage(0, 0);
  __syncthreads();
  int buf = 0;
  for (int kt = 0; kt < 16; ++kt) {
    if (kt < 15) stage(buf ^ 1, kt + 1);
    const short (*As)[32] = (const short(*)[32])(smem + buf * 8192);
    const short (*Bs)[32] = (const short(*)[32])(smem + buf * 8192 + 4096);
    b16x8 af[4], bf[4];
    #pragma unroll
    for (int mt = 0; mt < 4; ++mt) af[mt] = *(const b16x8*)&As[wm + mt * 16 + n16][quad * 8];
    #pragma unroll
    for (int nt = 0; nt < 4; ++nt) bf[nt] = *(const b16x8*)&Bs[wn + nt * 16 + n16][quad * 8];
    #pragma unroll
    for (int mt = 0; mt < 4; ++mt)
      #pragma unroll
      for (int nt = 0; nt < 4; ++nt)
        acc[mt][nt] = __builtin_amdgcn_mfma_f32_16x16x32_bf16(af[mt], bf[nt], acc[mt][nt], 0, 0, 0);
    __syncthreads();
    buf ^= 1;
  }

  #pragma unroll
  for (int mt = 0; mt < 4; ++mt) {
    int rowb = row0 + wm + mt * 16 + quad * 4;
    #pragma unroll
    for (int nt = 0; nt < 4; ++nt) {
      int colg = ncol0 + wn + nt * 16 + n16;
      #pragma unroll
      for (int r = 0; r < 4; ++r)
        out[(size_t)(rowb + r) * 512 + colg] = acc[mt][nt][r];
    }
  }
}

// ---------------------------------------------------------------------------
extern "C" void kernel_launch(void* const* d_in, const int* in_sizes, int n_in,
                              void* d_out, int out_size, void* d_ws, size_t ws_size,
                              hipStream_t stream) {
  const float* x    = (const float*)d_in[0];
  const float* Wq   = (const float*)d_in[1];
  const float* Wk   = (const float*)d_in[2];
  const float* Wv   = (const float*)d_in[3];
  const float* Wo   = (const float*)d_in[4];
  const float* relT = (const float*)d_in[5];
  const float* relP = (const float*)d_in[6];

  char* wsb = (char*)d_ws;
  const size_t SZ = (size_t)BL_ * C_ * 2;
  short* xb  = (short*)(wsb);
  short* WT  = (short*)(wsb + SZ);
  short* qb  = (short*)(wsb + SZ + 2097152);
  short* kb  = (short*)(wsb + 2 * SZ + 2097152);
  short* vTb = (short*)(wsb + 3 * SZ + 2097152);
  short* yat = (short*)(wsb + 4 * SZ + 2097152 + 4096);

  prep_kernel<<<dim3(4096), dim3(256), 0, stream>>>(x, Wq, Wk, Wv, Wo, xb, WT);
  qkv_kernel<<<dim3(96, 12), dim3(256), 0, stream>>>(xb, WT, qb, kb, vTb);
  attn_kernel<<<dim3(1536), dim3(128), 0, stream>>>(qb, kb, vTb, relT, relP, yat);
  proj_kernel<<<dim3(96, 4), dim3(256), 0, stream>>>(yat, WT, (float*)d_out);
}

// Round 8
// 157.373 us; speedup vs baseline: 1.7132x; 1.2208x over previous
//
#include <hip/hip_runtime.h>
#include <hip/hip_bf16.h>
#include <math.h>

#define B_  16
#define N_  16
#define T_  48
#define C_  512
#define H_  8
#define HD_ 64
#define L_  768
#define BL_ 12288

typedef __attribute__((ext_vector_type(8))) short b16x8;
typedef __attribute__((ext_vector_type(4))) float f32x4;
typedef __attribute__((ext_vector_type(2))) unsigned int u32x2;

__device__ __forceinline__ short f2b(float f) {
  __hip_bfloat16 h = __float2bfloat16(f);
  return *reinterpret_cast<short*>(&h);
}
// packed f32x2 -> bf16x2 (RNE), single VALU op
__device__ __forceinline__ unsigned cvt_pk_bf16(float a, float b) {
  unsigned d;
  asm("v_cvt_pk_bf16_f32 %0, %1, %2" : "=v"(d) : "v"(a), "v"(b));
  return d;
}
// 2^x, single transcendental VALU op (biases/scales pre-folded by log2e)
__device__ __forceinline__ float ex2(float x) {
  float d;
  asm("v_exp_f32 %0, %1" : "=v"(d) : "v"(x));
  return d;
}
// async global->LDS, 16B per lane; dest must be linear base + lane*16
__device__ __forceinline__ void gload16(const void* g, void* l) {
  __builtin_amdgcn_global_load_lds(
      (const __attribute__((address_space(1))) void*)g,
      (__attribute__((address_space(3))) void*)l, 16, 0, 0);
}

// ---------------------------------------------------------------------------
// prep: blocks [0,3072) cast x fp32->bf16; blocks [3072,4096) cast+transpose
// weights into WT[mat][n][k] (Wq pre-scaled by log2(e)/8 for exp2 softmax).
// ---------------------------------------------------------------------------
__global__ __launch_bounds__(256) void prep_kernel(
    const float* __restrict__ x,
    const float* __restrict__ Wq, const float* __restrict__ Wk,
    const float* __restrict__ Wv, const float* __restrict__ Wo,
    short* __restrict__ xb, short* __restrict__ WT)
{
  __shared__ float tile[32][33];
  int blk = blockIdx.x;
  int tid = threadIdx.x;
  if (blk < 3072) {
    int i = blk * 256 + tid;
    const float4* src = (const float4*)(x + (size_t)i * 8);
    float4 a = src[0], b = src[1];
    short tmp[8] = {f2b(a.x), f2b(a.y), f2b(a.z), f2b(a.w),
                    f2b(b.x), f2b(b.y), f2b(b.z), f2b(b.w)};
    *(b16x8*)(xb + (size_t)i * 8) = *(b16x8*)tmp;
  } else {
    int idx = blk - 3072;
    int mat = idx >> 8, rem = idx & 255;
    const float* W = (mat == 0) ? Wq : (mat == 1) ? Wk : (mat == 2) ? Wv : Wo;
    float scale = (mat == 0) ? 0.18033688f : 1.0f;   // log2(e)/8
    int k0 = (rem >> 4) * 32, n0 = (rem & 15) * 32;
    int tx = tid & 31, ty = tid >> 5;
    for (int i = ty; i < 32; i += 8) tile[i][tx] = W[(size_t)(k0 + i) * 512 + n0 + tx];
    __syncthreads();
    short* dst = WT + (size_t)mat * 262144;
    for (int i = ty; i < 32; i += 8)
      dst[(size_t)(n0 + i) * 512 + k0 + tx] = f2b(tile[tx][i] * scale);
  }
}

// ---------------------------------------------------------------------------
// QKV GEMM (R11): global_load_lds width-16 double-buffered staging.
//   q2,k2: [b][h][t][n][d]   vT2: [b][h][d][t][n]
// ---------------------------------------------------------------------------
__global__ __launch_bounds__(256) void qkv_kernel(
    const short* __restrict__ xb, const short* __restrict__ WT,
    short* __restrict__ q2, short* __restrict__ k2, short* __restrict__ vT2)
{
  __shared__ __align__(16) short smem[16384];  // 32KB: [buf][A 4096 | B 4096]
  int tid = threadIdx.x;
  int w = tid >> 6, lane = tid & 63, n16 = lane & 15, quad = lane >> 4;
  int bm = blockIdx.x, bn = blockIdx.y;
  int mat = bn >> 2;
  int ncol0 = (bn & 3) * 128;
  const short* Wt = WT + (size_t)mat * 262144;
  int bq = bm / 6;
  int rr0 = (bm % 6) * 128;

  f32x4 zero4 = {0.f, 0.f, 0.f, 0.f};
  f32x4 acc[4][4];
  #pragma unroll
  for (int mt = 0; mt < 4; ++mt)
    #pragma unroll
    for (int nt = 0; nt < 4; ++nt) acc[mt][nt] = zero4;

  const short* gA[2];
  const short* gB[2];
  #pragma unroll
  for (int i = 0; i < 2; ++i) {
    int r16 = w + 4 * i;
    int rr = rr0 + r16 * 16 + (lane >> 2);
    int pt = rr >> 4, pn = rr & 15;          // permuted row -> l = pn*48+pt
    gA[i] = xb + ((size_t)bq * 768 + pn * 48 + pt) * 512 + (lane & 3) * 8;
    gB[i] = Wt + (size_t)(ncol0 + r16 * 16 + (lane >> 2)) * 512 + (lane & 3) * 8;
  }
  int ldsoff = (w) * 512 + lane * 8;         // shorts, within a 4096-short tile

  auto stage = [&](int buf, int kt) {
    short* As = smem + buf * 8192;
    short* Bs = As + 4096;
    #pragma unroll
    for (int i = 0; i < 2; ++i) {
      gload16(gA[i] + kt * 32, As + i * 2048 + ldsoff);
      gload16(gB[i] + kt * 32, Bs + i * 2048 + ldsoff);
    }
  };

  int wm = (w >> 1) * 64, wn = (w & 1) * 64;
  stage(0, 0);
  __syncthreads();                           // vmcnt(0) drain + barrier
  int buf = 0;
  for (int kt = 0; kt < 16; ++kt) {
    if (kt < 15) stage(buf ^ 1, kt + 1);
    const short (*As)[32] = (const short(*)[32])(smem + buf * 8192);
    const short (*Bs)[32] = (const short(*)[32])(smem + buf * 8192 + 4096);
    b16x8 af[4], bf[4];
    #pragma unroll
    for (int mt = 0; mt < 4; ++mt) af[mt] = *(const b16x8*)&As[wm + mt * 16 + n16][quad * 8];
    #pragma unroll
    for (int nt = 0; nt < 4; ++nt) bf[nt] = *(const b16x8*)&Bs[wn + nt * 16 + n16][quad * 8];
    #pragma unroll
    for (int mt = 0; mt < 4; ++mt)
      #pragma unroll
      for (int nt = 0; nt < 4; ++nt)
        acc[mt][nt] = __builtin_amdgcn_mfma_f32_16x16x32_bf16(af[mt], bf[nt], acc[mt][nt], 0, 0, 0);
    __syncthreads();                         // waves done reading + next tile landed
    buf ^= 1;
  }

  // epilogue: 4 chunks of 32 tile-rows staged through LDS, vector stores out
  short (*Ls)[136] = (short(*)[136])smem;    // 32 x 136 (pad: aligned, spread banks)
  for (int c = 0; c < 4; ++c) {
    __syncthreads();
    if ((w >> 1) == (c >> 1)) {              // waves owning rows 32c..32c+31
      int mtb = (c & 1) * 2;
      #pragma unroll
      for (int mi = 0; mi < 2; ++mi) {
        #pragma unroll
        for (int nt = 0; nt < 4; ++nt)
          #pragma unroll
          for (int r = 0; r < 4; ++r)
            Ls[mi * 16 + quad * 4 + r][wn + nt * 16 + n16] = f2b(acc[mtb + mi][nt][r]);
      }
    }
    __syncthreads();
    int rrc = rr0 + c * 32;
    if (mat != 2) {
      short* dst = (mat == 0) ? q2 : k2;
      int row = tid >> 3, c0 = (tid & 7) * 16;
      int hhg = (ncol0 + c0) >> 6, d0 = (ncol0 + c0) & 63;
      short* dp = dst + ((size_t)(bq * 8 + hhg) * 768 + rrc + row) * 64 + d0;
      *(b16x8*)dp       = *(b16x8*)&Ls[row][c0];
      *(b16x8*)(dp + 8) = *(b16x8*)&Ls[row][c0 + 8];
    } else {
      int cp = tid & 63, r8 = (tid >> 6) * 8;
      int c0 = 2 * cp;
      int hhg = (ncol0 + c0) >> 6, d0 = (ncol0 + c0) & 63;
      short t0[8], t1[8];
      #pragma unroll
      for (int j = 0; j < 8; ++j) { t0[j] = Ls[r8 + j][c0]; t1[j] = Ls[r8 + j][c0 + 1]; }
      short* dp = vT2 + ((size_t)(bq * 8 + hhg) * 64 + d0) * 768 + rrc + r8;
      *(b16x8*)dp         = *(b16x8*)t0;
      *(b16x8*)(dp + 768) = *(b16x8*)t1;
    }
  }
}

// ---------------------------------------------------------------------------
// Attention (R12): LDS-staged K/V. The two waves of a block share (b,h) and
// previously each re-loaded identical K/V tiles from L2 direct-to-register
// (~200-400cy on the critical path per step). Now: cooperative reg-staged
// double-buffered LDS tiles (T14 async-STAGE: loads issued before compute,
// ds_write after), ONE barrier/step. Lockstep is exact: pair=2pg+wv gives
// both waves identical nA=pg+1, nB=24-pg. Conflict-free frag reads via
// granule-sequential layouts: K split by d-half into 2x[32][32], V [64][32]
// (lane granule = row*4+quad, the m97 [128][32] pattern). L2 traffic halved;
// step critical path starts at ~60cy ds_read instead of L2 round-trip.
// ---------------------------------------------------------------------------
__global__ __launch_bounds__(128, 3) void attn_kernel(
    const short* __restrict__ q2, const short* __restrict__ k2,
    const short* __restrict__ vT2,
    const float* __restrict__ relT, const float* __restrict__ relP,
    short* __restrict__ yatt)
{
  __shared__ __align__(16) short KV[2][4096];  // [buf]: Ks0[32][32] | Ks1[32][32] | Vs[64][32]
  __shared__ float btL[2][96];

  const float LOG2E = 1.44269504f;
  int tid = threadIdx.x;
  int wv = tid >> 6, lane = tid & 63, n16 = lane & 15, quad = lane >> 4;
  int blk = blockIdx.x;
  int h = blk & 7;                          // XCD-locality
  int g = blk >> 3;
  int pg = g % 12, b = g / 12;
  int pair = pg * 2 + wv;
  int qtA = pair, qtB = 47 - pair;
  int nA = pg + 1;                          // == (qtA+2)>>1 for BOTH waves
  int nB = 24 - pg;                         // == (qtB+2)>>1 for BOTH waves

  btL[wv][lane] = relT[(lane < 95 ? lane : 94) * 8 + h] * LOG2E;
  if (lane < 32) btL[wv][64 + lane] = relT[((64 + lane) < 95 ? 64 + lane : 94) * 8 + h] * LOG2E;

  // swapped layout: reg r = key particle quad*4+r, lane n16 = q particle
  float bpT[4];
  #pragma unroll
  for (int r = 0; r < 4; ++r)
    bpT[r] = relP[(quad * 4 + r - n16 + 15) * 8 + h] * LOG2E;

  size_t bh = (size_t)(b * 8 + h);
  const short* qb = q2 + bh * 49152;
  const short* kb = k2 + bh * 49152;
  const short* vb = vT2 + bh * 49152;

  b16x8 qA0 = *(const b16x8*)(qb + (qtA * 16 + n16) * 64 + quad * 8);
  b16x8 qA1 = *(const b16x8*)(qb + (qtA * 16 + n16) * 64 + quad * 8 + 32);
  b16x8 qB0 = *(const b16x8*)(qb + (qtB * 16 + n16) * 64 + quad * 8);
  b16x8 qB1 = *(const b16x8*)(qb + (qtB * 16 + n16) * 64 + quad * 8 + 32);

  f32x4 zero4 = {0.f, 0.f, 0.f, 0.f};
  f32x4 oA[4], oB[4];
  float psA = 0.f, psB = 0.f;
  #pragma unroll
  for (int nt = 0; nt < 4; ++nt) { oA[nt] = zero4; oB[nt] = zero4; }

  // --- cooperative staging: 128 threads cover K-tile (32x64) + V-tile (64x32)
  int krow = tid >> 3, kc8 = tid & 7;        // K slot: row 0..15 (+16 via s1), 16B chunk 0..7
  int vd   = tid >> 2, vkc = tid & 3;        // V slot: d 0..31 (+32 via s3), 16B chunk 0..3
  int kdst = (kc8 < 4 ? 0 : 1024) + krow * 32 + (kc8 & 3) * 8;   // Ks0 | Ks1
  int vdst = 2048 + vd * 32 + vkc * 8;                           // Vs
  b16x8 s0, s1, s2, s3;
  auto LOADR = [&](int kt2) {
    const short* kq = kb + (size_t)(kt2 * 32 + krow) * 64 + kc8 * 8;
    s0 = *(const b16x8*)kq;
    s1 = *(const b16x8*)(kq + 16 * 64);                          // rows +16
    const short* vq = vb + (size_t)vd * 768 + kt2 * 32 + vkc * 8;
    s2 = *(const b16x8*)vq;
    s3 = *(const b16x8*)(vq + (size_t)32 * 768);                 // d +32
  };
  auto WRITE = [&](int buf) {
    short* p = KV[buf];
    *(b16x8*)(p + kdst)       = s0;
    *(b16x8*)(p + kdst + 512) = s1;        // +16 rows * 32 shorts
    *(b16x8*)(p + vdst)        = s2;
    *(b16x8*)(p + vdst + 1024) = s3;       // +32 d * 32 shorts
  };

  // exp2+bias on S^T tile pair, pack to the PV A-fragment in-register.
  auto exp_pack = [&](const f32x4& s0v, const f32x4& s1v, float bt0, float bt1,
                      float& ps) -> b16x8 {
    float e00 = ex2(s0v[0] + bt0 + bpT[0]);
    float e01 = ex2(s0v[1] + bt0 + bpT[1]);
    float e02 = ex2(s0v[2] + bt0 + bpT[2]);
    float e03 = ex2(s0v[3] + bt0 + bpT[3]);
    float e10 = ex2(s1v[0] + bt1 + bpT[0]);
    float e11 = ex2(s1v[1] + bt1 + bpT[1]);
    float e12 = ex2(s1v[2] + bt1 + bpT[2]);
    float e13 = ex2(s1v[3] + bt1 + bpT[3]);
    ps += ((e00 + e01) + (e02 + e03)) + ((e10 + e11) + (e12 + e13));
    unsigned p0 = cvt_pk_bf16(e00, e01);
    unsigned p1 = cvt_pk_bf16(e02, e03);
    unsigned p2 = cvt_pk_bf16(e10, e11);
    unsigned p3 = cvt_pk_bf16(e12, e13);
    u32x2 a02 = __builtin_amdgcn_permlane32_swap(p0, p2, false, false);
    u32x2 z02 = __builtin_amdgcn_permlane16_swap(a02.x, a02.y, false, false);
    u32x2 a13 = __builtin_amdgcn_permlane32_swap(p1, p3, false, false);
    u32x2 z13 = __builtin_amdgcn_permlane16_swap(a13.x, a13.y, false, false);
    union { unsigned u[4]; b16x8 v; } r;
    r.u[0] = z02.x;
    r.u[1] = z13.x;
    r.u[2] = z02.y;
    r.u[3] = z13.y;
    return r.v;
  };

  // prologue: stage tile 0
  LOADR(0);
  WRITE(0);
  __syncthreads();

  int buf = 0;
  for (int kt2 = 0; kt2 < nB; ++kt2) {
    bool more = (kt2 + 1 < nB);              // wave-uniform, block-uniform
    if (more) LOADR(kt2 + 1);                // issue early: latency hides under compute

    const short* p = KV[buf];
    // K fragments (conflict-free: granule = n16*4+quad, sequential)
    b16x8 kf0 = *(const b16x8*)(p + n16 * 32 + quad * 8);
    b16x8 kf1 = *(const b16x8*)(p + 1024 + n16 * 32 + quad * 8);
    b16x8 kf2 = *(const b16x8*)(p + (16 + n16) * 32 + quad * 8);
    b16x8 kf3 = *(const b16x8*)(p + 1024 + (16 + n16) * 32 + quad * 8);
    b16x8 vf0 = *(const b16x8*)(p + 2048 + n16 * 32 + quad * 8);
    b16x8 vf1 = *(const b16x8*)(p + 2048 + (16 + n16) * 32 + quad * 8);
    b16x8 vf2 = *(const b16x8*)(p + 2048 + (32 + n16) * 32 + quad * 8);
    b16x8 vf3 = *(const b16x8*)(p + 2048 + (48 + n16) * 32 + quad * 8);

    int kt0 = kt2 * 2;
    bool doA = kt2 < nA;                     // wave-uniform
    f32x4 sB0 = zero4, sB1 = zero4;
    sB0 = __builtin_amdgcn_mfma_f32_16x16x32_bf16(kf0, qB0, sB0, 0, 0, 0);
    sB0 = __builtin_amdgcn_mfma_f32_16x16x32_bf16(kf1, qB1, sB0, 0, 0, 0);
    sB1 = __builtin_amdgcn_mfma_f32_16x16x32_bf16(kf2, qB0, sB1, 0, 0, 0);
    sB1 = __builtin_amdgcn_mfma_f32_16x16x32_bf16(kf3, qB1, sB1, 0, 0, 0);
    f32x4 sA0 = zero4, sA1 = zero4;
    if (doA) {
      sA0 = __builtin_amdgcn_mfma_f32_16x16x32_bf16(kf0, qA0, sA0, 0, 0, 0);
      sA0 = __builtin_amdgcn_mfma_f32_16x16x32_bf16(kf1, qA1, sA0, 0, 0, 0);
      sA1 = __builtin_amdgcn_mfma_f32_16x16x32_bf16(kf2, qA0, sA1, 0, 0, 0);
      sA1 = __builtin_amdgcn_mfma_f32_16x16x32_bf16(kf3, qA1, sA1, 0, 0, 0);
    }
    float btB0 = (kt0 <= qtB) ? btL[wv][kt0 - qtB + 47] : -1e30f;
    float btB1 = (kt0 + 1 <= qtB) ? btL[wv][kt0 + 1 - qtB + 47] : -1e30f;
    b16x8 pfB = exp_pack(sB0, sB1, btB0, btB1, psB);
    oB[0] = __builtin_amdgcn_mfma_f32_16x16x32_bf16(pfB, vf0, oB[0], 0, 0, 0);
    oB[1] = __builtin_amdgcn_mfma_f32_16x16x32_bf16(pfB, vf1, oB[1], 0, 0, 0);
    oB[2] = __builtin_amdgcn_mfma_f32_16x16x32_bf16(pfB, vf2, oB[2], 0, 0, 0);
    oB[3] = __builtin_amdgcn_mfma_f32_16x16x32_bf16(pfB, vf3, oB[3], 0, 0, 0);
    if (doA) {
      float btA0 = (kt0 <= qtA) ? btL[wv][kt0 - qtA + 47] : -1e30f;
      float btA1 = (kt0 + 1 <= qtA) ? btL[wv][kt0 + 1 - qtA + 47] : -1e30f;
      b16x8 pfA = exp_pack(sA0, sA1, btA0, btA1, psA);
      oA[0] = __builtin_amdgcn_mfma_f32_16x16x32_bf16(pfA, vf0, oA[0], 0, 0, 0);
      oA[1] = __builtin_amdgcn_mfma_f32_16x16x32_bf16(pfA, vf1, oA[1], 0, 0, 0);
      oA[2] = __builtin_amdgcn_mfma_f32_16x16x32_bf16(pfA, vf2, oA[2], 0, 0, 0);
      oA[3] = __builtin_amdgcn_mfma_f32_16x16x32_bf16(pfA, vf3, oA[3], 0, 0, 0);
    }

    if (more) WRITE(buf ^ 1);                // vmcnt wait lands HERE (after compute)
    __syncthreads();                         // writes visible; all reads of buf done
    buf ^= 1;
  }

  // denom: per-lane partial (q = n16, keys split across quads) -> full sum
  psA += __shfl_xor(psA, 16); psA += __shfl_xor(psA, 32);
  psB += __shfl_xor(psB, 16); psB += __shfl_xor(psB, 32);
  float invA = 1.0f / psA, invB = 1.0f / psB;
  float pnA[4], pnB[4];
  #pragma unroll
  for (int r = 0; r < 4; ++r) {
    pnA[r] = __shfl(invA, quad * 4 + r);
    pnB[r] = __shfl(invB, quad * 4 + r);
  }

  #pragma unroll
  for (int nt = 0; nt < 4; ++nt) {
    int c = h * 64 + nt * 16 + n16;
    #pragma unroll
    for (int r = 0; r < 4; ++r) {
      int qn = quad * 4 + r;
      yatt[((size_t)b * 768 + qn * 48 + qtA) * 512 + c] = f2b(oA[nt][r] * pnA[r]);
      yatt[((size_t)b * 768 + qn * 48 + qtB) * 512 + c] = f2b(oB[nt][r] * pnB[r]);
    }
  }
}

// ---------------------------------------------------------------------------
// proj (R11): yatt(12288x512,bf16) @ WoT -> out fp32, global_load_lds staging
// ---------------------------------------------------------------------------
__global__ __launch_bounds__(256) void proj_kernel(
    const short* __restrict__ yatt, const short* __restrict__ WT,
    float* __restrict__ out)
{
  __shared__ __align__(16) short smem[16384];  // 32KB double buffer
  int tid = threadIdx.x;
  int w = tid >> 6, lane = tid & 63, n16 = lane & 15, quad = lane >> 4;
  int row0 = blockIdx.x * 128;
  int ncol0 = blockIdx.y * 128;
  const short* Wt = WT + (size_t)3 * 262144;

  f32x4 zero4 = {0.f, 0.f, 0.f, 0.f};
  f32x4 acc[4][4];
  #pragma unroll
  for (int mt = 0; mt < 4; ++mt)
    #pragma unroll
    for (int nt = 0; nt < 4; ++nt) acc[mt][nt] = zero4;

  const short* gA[2];
  const short* gB[2];
  #pragma unroll
  for (int i = 0; i < 2; ++i) {
    int r16 = w + 4 * i;
    gA[i] = yatt + (size_t)(row0 + r16 * 16 + (lane >> 2)) * 512 + (lane & 3) * 8;
    gB[i] = Wt + (size_t)(ncol0 + r16 * 16 + (lane >> 2)) * 512 + (lane & 3) * 8;
  }
  int ldsoff = w * 512 + lane * 8;

  auto stage = [&](int buf, int kt) {
    short* As = smem + buf * 8192;
    short* Bs = As + 4096;
    #pragma unroll
    for (int i = 0; i < 2; ++i) {
      gload16(gA[i] + kt * 32, As + i * 2048 + ldsoff);
      gload16(gB[i] + kt * 32, Bs + i * 2048 + ldsoff);
    }
  };

  int wm = (w >> 1) * 64, wn = (w & 1) * 64;
  stage(0, 0);
  __syncthreads();
  int buf = 0;
  for (int kt = 0; kt < 16; ++kt) {
    if (kt < 15) stage(buf ^ 1, kt + 1);
    const short (*As)[32] = (const short(*)[32])(smem + buf * 8192);
    const short (*Bs)[32] = (const short(*)[32])(smem + buf * 8192 + 4096);
    b16x8 af[4], bf[4];
    #pragma unroll
    for (int mt = 0; mt < 4; ++mt) af[mt] = *(const b16x8*)&As[wm + mt * 16 + n16][quad * 8];
    #pragma unroll
    for (int nt = 0; nt < 4; ++nt) bf[nt] = *(const b16x8*)&Bs[wn + nt * 16 + n16][quad * 8];
    #pragma unroll
    for (int mt = 0; mt < 4; ++mt)
      #pragma unroll
      for (int nt = 0; nt < 4; ++nt)
        acc[mt][nt] = __builtin_amdgcn_mfma_f32_16x16x32_bf16(af[mt], bf[nt], acc[mt][nt], 0, 0, 0);
    __syncthreads();
    buf ^= 1;
  }

  #pragma unroll
  for (int mt = 0; mt < 4; ++mt) {
    int rowb = row0 + wm + mt * 16 + quad * 4;
    #pragma unroll
    for (int nt = 0; nt < 4; ++nt) {
      int colg = ncol0 + wn + nt * 16 + n16;
      #pragma unroll
      for (int r = 0; r < 4; ++r)
        out[(size_t)(rowb + r) * 512 + colg] = acc[mt][nt][r];
    }
  }
}

// ---------------------------------------------------------------------------
extern "C" void kernel_launch(void* const* d_in, const int* in_sizes, int n_in,
                              void* d_out, int out_size, void* d_ws, size_t ws_size,
                              hipStream_t stream) {
  const float* x    = (const float*)d_in[0];
  const float* Wq   = (const float*)d_in[1];
  const float* Wk   = (const float*)d_in[2];
  const float* Wv   = (const float*)d_in[3];
  const float* Wo   = (const float*)d_in[4];
  const float* relT = (const float*)d_in[5];
  const float* relP = (const float*)d_in[6];

  char* wsb = (char*)d_ws;
  const size_t SZ = (size_t)BL_ * C_ * 2;
  short* xb  = (short*)(wsb);
  short* WT  = (short*)(wsb + SZ);
  short* qb  = (short*)(wsb + SZ + 2097152);
  short* kb  = (short*)(wsb + 2 * SZ + 2097152);
  short* vTb = (short*)(wsb + 3 * SZ + 2097152);
  short* yat = (short*)(wsb + 4 * SZ + 2097152 + 4096);

  prep_kernel<<<dim3(4096), dim3(256), 0, stream>>>(x, Wq, Wk, Wv, Wo, xb, WT);
  qkv_kernel<<<dim3(96, 12), dim3(256), 0, stream>>>(xb, WT, qb, kb, vTb);
  attn_kernel<<<dim3(1536), dim3(128), 0, stream>>>(qb, kb, vTb, relT, relP, yat);
  proj_kernel<<<dim3(96, 4), dim3(256), 0, stream>>>(yat, WT, (float*)d_out);
}

// Round 9
// 156.807 us; speedup vs baseline: 1.7194x; 1.0036x over previous
//
#include <hip/hip_runtime.h>
#include <hip/hip_bf16.h>
#include <math.h>

#define B_  16
#define N_  16
#define T_  48
#define C_  512
#define H_  8
#define HD_ 64
#define L_  768
#define BL_ 12288

typedef __attribute__((ext_vector_type(8))) short b16x8;
typedef __attribute__((ext_vector_type(4))) float f32x4;
typedef __attribute__((ext_vector_type(2))) unsigned int u32x2;

__device__ __forceinline__ short f2b(float f) {
  __hip_bfloat16 h = __float2bfloat16(f);
  return *reinterpret_cast<short*>(&h);
}
// packed f32x2 -> bf16x2 (RNE), single VALU op
__device__ __forceinline__ unsigned cvt_pk_bf16(float a, float b) {
  unsigned d;
  asm("v_cvt_pk_bf16_f32 %0, %1, %2" : "=v"(d) : "v"(a), "v"(b));
  return d;
}
// 2^x, single transcendental VALU op (biases/scales pre-folded by log2e)
__device__ __forceinline__ float ex2(float x) {
  float d;
  asm("v_exp_f32 %0, %1" : "=v"(d) : "v"(x));
  return d;
}
// async global->LDS, 16B per lane; dest must be linear base + lane*16
__device__ __forceinline__ void gload16(const void* g, void* l) {
  __builtin_amdgcn_global_load_lds(
      (const __attribute__((address_space(1))) void*)g,
      (__attribute__((address_space(3))) void*)l, 16, 0, 0);
}

// ---------------------------------------------------------------------------
// prep: blocks [0,3072) cast x fp32->bf16; blocks [3072,4096) cast+transpose
// weights into WT[mat][n][k] (Wq pre-scaled by log2(e)/8 for exp2 softmax).
// ---------------------------------------------------------------------------
__global__ __launch_bounds__(256) void prep_kernel(
    const float* __restrict__ x,
    const float* __restrict__ Wq, const float* __restrict__ Wk,
    const float* __restrict__ Wv, const float* __restrict__ Wo,
    short* __restrict__ xb, short* __restrict__ WT)
{
  __shared__ float tile[32][33];
  int blk = blockIdx.x;
  int tid = threadIdx.x;
  if (blk < 3072) {
    int i = blk * 256 + tid;
    const float4* src = (const float4*)(x + (size_t)i * 8);
    float4 a = src[0], b = src[1];
    short tmp[8] = {f2b(a.x), f2b(a.y), f2b(a.z), f2b(a.w),
                    f2b(b.x), f2b(b.y), f2b(b.z), f2b(b.w)};
    *(b16x8*)(xb + (size_t)i * 8) = *(b16x8*)tmp;
  } else {
    int idx = blk - 3072;
    int mat = idx >> 8, rem = idx & 255;
    const float* W = (mat == 0) ? Wq : (mat == 1) ? Wk : (mat == 2) ? Wv : Wo;
    float scale = (mat == 0) ? 0.18033688f : 1.0f;   // log2(e)/8
    int k0 = (rem >> 4) * 32, n0 = (rem & 15) * 32;
    int tx = tid & 31, ty = tid >> 5;
    for (int i = ty; i < 32; i += 8) tile[i][tx] = W[(size_t)(k0 + i) * 512 + n0 + tx];
    __syncthreads();
    short* dst = WT + (size_t)mat * 262144;
    for (int i = ty; i < 32; i += 8)
      dst[(size_t)(n0 + i) * 512 + k0 + tx] = f2b(tile[tx][i] * scale);
  }
}

// ---------------------------------------------------------------------------
// QKV GEMM (R11): global_load_lds width-16 double-buffered staging.
//   q2,k2: [b][h][t][n][d]   vT2: [b][h][d][t][n]
// ---------------------------------------------------------------------------
__global__ __launch_bounds__(256) void qkv_kernel(
    const short* __restrict__ xb, const short* __restrict__ WT,
    short* __restrict__ q2, short* __restrict__ k2, short* __restrict__ vT2)
{
  __shared__ __align__(16) short smem[16384];  // 32KB: [buf][A 4096 | B 4096]
  int tid = threadIdx.x;
  int w = tid >> 6, lane = tid & 63, n16 = lane & 15, quad = lane >> 4;
  int bm = blockIdx.x, bn = blockIdx.y;
  int mat = bn >> 2;
  int ncol0 = (bn & 3) * 128;
  const short* Wt = WT + (size_t)mat * 262144;
  int bq = bm / 6;
  int rr0 = (bm % 6) * 128;

  f32x4 zero4 = {0.f, 0.f, 0.f, 0.f};
  f32x4 acc[4][4];
  #pragma unroll
  for (int mt = 0; mt < 4; ++mt)
    #pragma unroll
    for (int nt = 0; nt < 4; ++nt) acc[mt][nt] = zero4;

  const short* gA[2];
  const short* gB[2];
  #pragma unroll
  for (int i = 0; i < 2; ++i) {
    int r16 = w + 4 * i;
    int rr = rr0 + r16 * 16 + (lane >> 2);
    int pt = rr >> 4, pn = rr & 15;          // permuted row -> l = pn*48+pt
    gA[i] = xb + ((size_t)bq * 768 + pn * 48 + pt) * 512 + (lane & 3) * 8;
    gB[i] = Wt + (size_t)(ncol0 + r16 * 16 + (lane >> 2)) * 512 + (lane & 3) * 8;
  }
  int ldsoff = (w) * 512 + lane * 8;         // shorts, within a 4096-short tile

  auto stage = [&](int buf, int kt) {
    short* As = smem + buf * 8192;
    short* Bs = As + 4096;
    #pragma unroll
    for (int i = 0; i < 2; ++i) {
      gload16(gA[i] + kt * 32, As + i * 2048 + ldsoff);
      gload16(gB[i] + kt * 32, Bs + i * 2048 + ldsoff);
    }
  };

  int wm = (w >> 1) * 64, wn = (w & 1) * 64;
  stage(0, 0);
  __syncthreads();                           // vmcnt(0) drain + barrier
  int buf = 0;
  for (int kt = 0; kt < 16; ++kt) {
    if (kt < 15) stage(buf ^ 1, kt + 1);
    const short (*As)[32] = (const short(*)[32])(smem + buf * 8192);
    const short (*Bs)[32] = (const short(*)[32])(smem + buf * 8192 + 4096);
    b16x8 af[4], bf[4];
    #pragma unroll
    for (int mt = 0; mt < 4; ++mt) af[mt] = *(const b16x8*)&As[wm + mt * 16 + n16][quad * 8];
    #pragma unroll
    for (int nt = 0; nt < 4; ++nt) bf[nt] = *(const b16x8*)&Bs[wn + nt * 16 + n16][quad * 8];
    #pragma unroll
    for (int mt = 0; mt < 4; ++mt)
      #pragma unroll
      for (int nt = 0; nt < 4; ++nt)
        acc[mt][nt] = __builtin_amdgcn_mfma_f32_16x16x32_bf16(af[mt], bf[nt], acc[mt][nt], 0, 0, 0);
    __syncthreads();                         // waves done reading + next tile landed
    buf ^= 1;
  }

  // epilogue: 4 chunks of 32 tile-rows staged through LDS, vector stores out
  short (*Ls)[136] = (short(*)[136])smem;    // 32 x 136 (pad: aligned, spread banks)
  for (int c = 0; c < 4; ++c) {
    __syncthreads();
    if ((w >> 1) == (c >> 1)) {              // waves owning rows 32c..32c+31
      int mtb = (c & 1) * 2;
      #pragma unroll
      for (int mi = 0; mi < 2; ++mi) {
        #pragma unroll
        for (int nt = 0; nt < 4; ++nt)
          #pragma unroll
          for (int r = 0; r < 4; ++r)
            Ls[mi * 16 + quad * 4 + r][wn + nt * 16 + n16] = f2b(acc[mtb + mi][nt][r]);
      }
    }
    __syncthreads();
    int rrc = rr0 + c * 32;
    if (mat != 2) {
      short* dst = (mat == 0) ? q2 : k2;
      int row = tid >> 3, c0 = (tid & 7) * 16;
      int hhg = (ncol0 + c0) >> 6, d0 = (ncol0 + c0) & 63;
      short* dp = dst + ((size_t)(bq * 8 + hhg) * 768 + rrc + row) * 64 + d0;
      *(b16x8*)dp       = *(b16x8*)&Ls[row][c0];
      *(b16x8*)(dp + 8) = *(b16x8*)&Ls[row][c0 + 8];
    } else {
      int cp = tid & 63, r8 = (tid >> 6) * 8;
      int c0 = 2 * cp;
      int hhg = (ncol0 + c0) >> 6, d0 = (ncol0 + c0) & 63;
      short t0[8], t1[8];
      #pragma unroll
      for (int j = 0; j < 8; ++j) { t0[j] = Ls[r8 + j][c0]; t1[j] = Ls[r8 + j][c0 + 1]; }
      short* dp = vT2 + ((size_t)(bq * 8 + hhg) * 64 + d0) * 768 + rrc + r8;
      *(b16x8*)dp         = *(b16x8*)t0;
      *(b16x8*)(dp + 768) = *(b16x8*)t1;
    }
  }
}

// ---------------------------------------------------------------------------
// Attention (R13): 4 waves/block, TWO pg-pairs sharing one K/V staging.
// R12 proved the LDS-staged K/V regime (attn 64->~30us); this merges blocks
// 2:1 so 256 threads cover the same 8KB tile (staging per thread HALVED,
// K/V L2 traffic halved) and SIMD occupancy rises 3->4 waves (launch_bounds
// (256,4): cap 128 >= ~110 state, no spill). Wave w handles pair=4*pgg+w;
// all waves loop to block-uniform nBmax with wave-uniform doB/doA guards
// (every barrier hit by all 4 waves; <=4% idle trailing step). T5 setprio
// wraps MFMA clusters (+4-7% measured on phase-diverse attn).
// ---------------------------------------------------------------------------
__global__ __launch_bounds__(256, 4) void attn_kernel(
    const short* __restrict__ q2, const short* __restrict__ k2,
    const short* __restrict__ vT2,
    const float* __restrict__ relT, const float* __restrict__ relP,
    short* __restrict__ yatt)
{
  __shared__ __align__(16) short KV[2][4096];  // [buf]: Ks0[32][32] | Ks1[32][32] | Vs[64][32]
  __shared__ float btL[96];

  const float LOG2E = 1.44269504f;
  int tid = threadIdx.x;
  int w = tid >> 6, lane = tid & 63, n16 = lane & 15, quad = lane >> 4;
  int blk = blockIdx.x;                     // 768 = (16b * 6pgg) * 8h
  int h = blk & 7;                          // XCD-locality
  int g = blk >> 3;                         // 0..95
  int pgg = g % 6, b = g / 6;
  int pairq = pgg * 4 + w;                  // 0..23, unique per wave
  int qtA = pairq, qtB = 47 - pairq;
  int nAw = (qtA + 2) >> 1;                 // wave-local step counts
  int nBw = (qtB + 2) >> 1;
  int nBmax = 24 - 2 * pgg;                 // block-uniform loop bound (= max nBw)

  if (tid < 96) btL[tid] = relT[(tid < 95 ? tid : 94) * 8 + h] * LOG2E;

  // swapped layout: reg r = key particle quad*4+r, lane n16 = q particle
  float bpT[4];
  #pragma unroll
  for (int r = 0; r < 4; ++r)
    bpT[r] = relP[(quad * 4 + r - n16 + 15) * 8 + h] * LOG2E;

  size_t bh = (size_t)(b * 8 + h);
  const short* qb = q2 + bh * 49152;
  const short* kb = k2 + bh * 49152;
  const short* vb = vT2 + bh * 49152;

  b16x8 qA0 = *(const b16x8*)(qb + (qtA * 16 + n16) * 64 + quad * 8);
  b16x8 qA1 = *(const b16x8*)(qb + (qtA * 16 + n16) * 64 + quad * 8 + 32);
  b16x8 qB0 = *(const b16x8*)(qb + (qtB * 16 + n16) * 64 + quad * 8);
  b16x8 qB1 = *(const b16x8*)(qb + (qtB * 16 + n16) * 64 + quad * 8 + 32);

  f32x4 zero4 = {0.f, 0.f, 0.f, 0.f};
  f32x4 oA[4], oB[4];
  float psA = 0.f, psB = 0.f;
  #pragma unroll
  for (int nt = 0; nt < 4; ++nt) { oA[nt] = zero4; oB[nt] = zero4; }

  // --- cooperative staging: 256 threads cover K (32x64) + V (64x32), 1 load each
  int krow = tid >> 3, kc8 = tid & 7;        // K: row 0..31, 16B chunk 0..7
  int vd   = tid >> 2, vkc = tid & 3;        // V: d 0..63, 16B chunk 0..3
  int kdst = (kc8 < 4 ? 0 : 1024) + krow * 32 + (kc8 & 3) * 8;   // Ks0 | Ks1 (d-halves)
  int vdst = 2048 + vd * 32 + vkc * 8;                           // Vs
  b16x8 s0, s2;
  auto LOADR = [&](int kt2) {
    s0 = *(const b16x8*)(kb + (size_t)(kt2 * 32 + krow) * 64 + kc8 * 8);
    s2 = *(const b16x8*)(vb + (size_t)vd * 768 + kt2 * 32 + vkc * 8);
  };
  auto WRITE = [&](int buf) {
    *(b16x8*)(KV[buf] + kdst) = s0;
    *(b16x8*)(KV[buf] + vdst) = s2;
  };

  // exp2+bias on S^T tile pair, pack to the PV A-fragment in-register.
  auto exp_pack = [&](const f32x4& s0v, const f32x4& s1v, float bt0, float bt1,
                      float& ps) -> b16x8 {
    float e00 = ex2(s0v[0] + bt0 + bpT[0]);
    float e01 = ex2(s0v[1] + bt0 + bpT[1]);
    float e02 = ex2(s0v[2] + bt0 + bpT[2]);
    float e03 = ex2(s0v[3] + bt0 + bpT[3]);
    float e10 = ex2(s1v[0] + bt1 + bpT[0]);
    float e11 = ex2(s1v[1] + bt1 + bpT[1]);
    float e12 = ex2(s1v[2] + bt1 + bpT[2]);
    float e13 = ex2(s1v[3] + bt1 + bpT[3]);
    ps += ((e00 + e01) + (e02 + e03)) + ((e10 + e11) + (e12 + e13));
    unsigned p0 = cvt_pk_bf16(e00, e01);
    unsigned p1 = cvt_pk_bf16(e02, e03);
    unsigned p2 = cvt_pk_bf16(e10, e11);
    unsigned p3 = cvt_pk_bf16(e12, e13);
    u32x2 a02 = __builtin_amdgcn_permlane32_swap(p0, p2, false, false);
    u32x2 z02 = __builtin_amdgcn_permlane16_swap(a02.x, a02.y, false, false);
    u32x2 a13 = __builtin_amdgcn_permlane32_swap(p1, p3, false, false);
    u32x2 z13 = __builtin_amdgcn_permlane16_swap(a13.x, a13.y, false, false);
    union { unsigned u[4]; b16x8 v; } r;
    r.u[0] = z02.x;
    r.u[1] = z13.x;
    r.u[2] = z02.y;
    r.u[3] = z13.y;
    return r.v;
  };

  // prologue: stage tile 0 (also covers btL visibility)
  LOADR(0);
  WRITE(0);
  __syncthreads();

  int buf = 0;
  for (int kt2 = 0; kt2 < nBmax; ++kt2) {
    bool more = (kt2 + 1 < nBmax);           // block-uniform
    if (more) LOADR(kt2 + 1);                // issue early: latency hides under compute

    bool doB = kt2 < nBw;                    // wave-uniform
    bool doA = kt2 < nAw;                    // wave-uniform, doA => doB
    if (doB) {
      const short* p = KV[buf];
      b16x8 kf0 = *(const b16x8*)(p + n16 * 32 + quad * 8);
      b16x8 kf1 = *(const b16x8*)(p + 1024 + n16 * 32 + quad * 8);
      b16x8 kf2 = *(const b16x8*)(p + (16 + n16) * 32 + quad * 8);
      b16x8 kf3 = *(const b16x8*)(p + 1024 + (16 + n16) * 32 + quad * 8);
      b16x8 vf0 = *(const b16x8*)(p + 2048 + n16 * 32 + quad * 8);
      b16x8 vf1 = *(const b16x8*)(p + 2048 + (16 + n16) * 32 + quad * 8);
      b16x8 vf2 = *(const b16x8*)(p + 2048 + (32 + n16) * 32 + quad * 8);
      b16x8 vf3 = *(const b16x8*)(p + 2048 + (48 + n16) * 32 + quad * 8);

      int kt0 = kt2 * 2;
      __builtin_amdgcn_s_setprio(1);
      f32x4 sB0 = zero4, sB1 = zero4;
      sB0 = __builtin_amdgcn_mfma_f32_16x16x32_bf16(kf0, qB0, sB0, 0, 0, 0);
      sB0 = __builtin_amdgcn_mfma_f32_16x16x32_bf16(kf1, qB1, sB0, 0, 0, 0);
      sB1 = __builtin_amdgcn_mfma_f32_16x16x32_bf16(kf2, qB0, sB1, 0, 0, 0);
      sB1 = __builtin_amdgcn_mfma_f32_16x16x32_bf16(kf3, qB1, sB1, 0, 0, 0);
      f32x4 sA0 = zero4, sA1 = zero4;
      if (doA) {
        sA0 = __builtin_amdgcn_mfma_f32_16x16x32_bf16(kf0, qA0, sA0, 0, 0, 0);
        sA0 = __builtin_amdgcn_mfma_f32_16x16x32_bf16(kf1, qA1, sA0, 0, 0, 0);
        sA1 = __builtin_amdgcn_mfma_f32_16x16x32_bf16(kf2, qA0, sA1, 0, 0, 0);
        sA1 = __builtin_amdgcn_mfma_f32_16x16x32_bf16(kf3, qA1, sA1, 0, 0, 0);
      }
      __builtin_amdgcn_s_setprio(0);
      float btB0 = (kt0 <= qtB) ? btL[kt0 - qtB + 47] : -1e30f;
      float btB1 = (kt0 + 1 <= qtB) ? btL[kt0 + 1 - qtB + 47] : -1e30f;
      b16x8 pfB = exp_pack(sB0, sB1, btB0, btB1, psB);
      __builtin_amdgcn_s_setprio(1);
      oB[0] = __builtin_amdgcn_mfma_f32_16x16x32_bf16(pfB, vf0, oB[0], 0, 0, 0);
      oB[1] = __builtin_amdgcn_mfma_f32_16x16x32_bf16(pfB, vf1, oB[1], 0, 0, 0);
      oB[2] = __builtin_amdgcn_mfma_f32_16x16x32_bf16(pfB, vf2, oB[2], 0, 0, 0);
      oB[3] = __builtin_amdgcn_mfma_f32_16x16x32_bf16(pfB, vf3, oB[3], 0, 0, 0);
      __builtin_amdgcn_s_setprio(0);
      if (doA) {
        float btA0 = (kt0 <= qtA) ? btL[kt0 - qtA + 47] : -1e30f;
        float btA1 = (kt0 + 1 <= qtA) ? btL[kt0 + 1 - qtA + 47] : -1e30f;
        b16x8 pfA = exp_pack(sA0, sA1, btA0, btA1, psA);
        __builtin_amdgcn_s_setprio(1);
        oA[0] = __builtin_amdgcn_mfma_f32_16x16x32_bf16(pfA, vf0, oA[0], 0, 0, 0);
        oA[1] = __builtin_amdgcn_mfma_f32_16x16x32_bf16(pfA, vf1, oA[1], 0, 0, 0);
        oA[2] = __builtin_amdgcn_mfma_f32_16x16x32_bf16(pfA, vf2, oA[2], 0, 0, 0);
        oA[3] = __builtin_amdgcn_mfma_f32_16x16x32_bf16(pfA, vf3, oA[3], 0, 0, 0);
        __builtin_amdgcn_s_setprio(0);
      }
    }

    if (more) WRITE(buf ^ 1);                // vmcnt wait lands HERE (after compute)
    __syncthreads();                         // writes visible; all reads of buf done
    buf ^= 1;
  }

  // denom: per-lane partial (q = n16, keys split across quads) -> full sum
  psA += __shfl_xor(psA, 16); psA += __shfl_xor(psA, 32);
  psB += __shfl_xor(psB, 16); psB += __shfl_xor(psB, 32);
  float invA = 1.0f / psA, invB = 1.0f / psB;
  float pnA[4], pnB[4];
  #pragma unroll
  for (int r = 0; r < 4; ++r) {
    pnA[r] = __shfl(invA, quad * 4 + r);
    pnB[r] = __shfl(invB, quad * 4 + r);
  }

  #pragma unroll
  for (int nt = 0; nt < 4; ++nt) {
    int c = h * 64 + nt * 16 + n16;
    #pragma unroll
    for (int r = 0; r < 4; ++r) {
      int qn = quad * 4 + r;
      yatt[((size_t)b * 768 + qn * 48 + qtA) * 512 + c] = f2b(oA[nt][r] * pnA[r]);
      yatt[((size_t)b * 768 + qn * 48 + qtB) * 512 + c] = f2b(oB[nt][r] * pnB[r]);
    }
  }
}

// ---------------------------------------------------------------------------
// proj (R11): yatt(12288x512,bf16) @ WoT -> out fp32, global_load_lds staging
// ---------------------------------------------------------------------------
__global__ __launch_bounds__(256) void proj_kernel(
    const short* __restrict__ yatt, const short* __restrict__ WT,
    float* __restrict__ out)
{
  __shared__ __align__(16) short smem[16384];  // 32KB double buffer
  int tid = threadIdx.x;
  int w = tid >> 6, lane = tid & 63, n16 = lane & 15, quad = lane >> 4;
  int row0 = blockIdx.x * 128;
  int ncol0 = blockIdx.y * 128;
  const short* Wt = WT + (size_t)3 * 262144;

  f32x4 zero4 = {0.f, 0.f, 0.f, 0.f};
  f32x4 acc[4][4];
  #pragma unroll
  for (int mt = 0; mt < 4; ++mt)
    #pragma unroll
    for (int nt = 0; nt < 4; ++nt) acc[mt][nt] = zero4;

  const short* gA[2];
  const short* gB[2];
  #pragma unroll
  for (int i = 0; i < 2; ++i) {
    int r16 = w + 4 * i;
    gA[i] = yatt + (size_t)(row0 + r16 * 16 + (lane >> 2)) * 512 + (lane & 3) * 8;
    gB[i] = Wt + (size_t)(ncol0 + r16 * 16 + (lane >> 2)) * 512 + (lane & 3) * 8;
  }
  int ldsoff = w * 512 + lane * 8;

  auto stage = [&](int buf, int kt) {
    short* As = smem + buf * 8192;
    short* Bs = As + 4096;
    #pragma unroll
    for (int i = 0; i < 2; ++i) {
      gload16(gA[i] + kt * 32, As + i * 2048 + ldsoff);
      gload16(gB[i] + kt * 32, Bs + i * 2048 + ldsoff);
    }
  };

  int wm = (w >> 1) * 64, wn = (w & 1) * 64;
  stage(0, 0);
  __syncthreads();
  int buf = 0;
  for (int kt = 0; kt < 16; ++kt) {
    if (kt < 15) stage(buf ^ 1, kt + 1);
    const short (*As)[32] = (const short(*)[32])(smem + buf * 8192);
    const short (*Bs)[32] = (const short(*)[32])(smem + buf * 8192 + 4096);
    b16x8 af[4], bf[4];
    #pragma unroll
    for (int mt = 0; mt < 4; ++mt) af[mt] = *(const b16x8*)&As[wm + mt * 16 + n16][quad * 8];
    #pragma unroll
    for (int nt = 0; nt < 4; ++nt) bf[nt] = *(const b16x8*)&Bs[wn + nt * 16 + n16][quad * 8];
    #pragma unroll
    for (int mt = 0; mt < 4; ++mt)
      #pragma unroll
      for (int nt = 0; nt < 4; ++nt)
        acc[mt][nt] = __builtin_amdgcn_mfma_f32_16x16x32_bf16(af[mt], bf[nt], acc[mt][nt], 0, 0, 0);
    __syncthreads();
    buf ^= 1;
  }

  #pragma unroll
  for (int mt = 0; mt < 4; ++mt) {
    int rowb = row0 + wm + mt * 16 + quad * 4;
    #pragma unroll
    for (int nt = 0; nt < 4; ++nt) {
      int colg = ncol0 + wn + nt * 16 + n16;
      #pragma unroll
      for (int r = 0; r < 4; ++r)
        out[(size_t)(rowb + r) * 512 + colg] = acc[mt][nt][r];
    }
  }
}

// ---------------------------------------------------------------------------
extern "C" void kernel_launch(void* const* d_in, const int* in_sizes, int n_in,
                              void* d_out, int out_size, void* d_ws, size_t ws_size,
                              hipStream_t stream) {
  const float* x    = (const float*)d_in[0];
  const float* Wq   = (const float*)d_in[1];
  const float* Wk   = (const float*)d_in[2];
  const float* Wv   = (const float*)d_in[3];
  const float* Wo   = (const float*)d_in[4];
  const float* relT = (const float*)d_in[5];
  const float* relP = (const float*)d_in[6];

  char* wsb = (char*)d_ws;
  const size_t SZ = (size_t)BL_ * C_ * 2;
  short* xb  = (short*)(wsb);
  short* WT  = (short*)(wsb + SZ);
  short* qb  = (short*)(wsb + SZ + 2097152);
  short* kb  = (short*)(wsb + 2 * SZ + 2097152);
  short* vTb = (short*)(wsb + 3 * SZ + 2097152);
  short* yat = (short*)(wsb + 4 * SZ + 2097152 + 4096);

  prep_kernel<<<dim3(4096), dim3(256), 0, stream>>>(x, Wq, Wk, Wv, Wo, xb, WT);
  qkv_kernel<<<dim3(96, 12), dim3(256), 0, stream>>>(xb, WT, qb, kb, vTb);
  attn_kernel<<<dim3(768), dim3(256), 0, stream>>>(qb, kb, vTb, relT, relP, yat);
  proj_kernel<<<dim3(96, 4), dim3(256), 0, stream>>>(yat, WT, (float*)d_out);
}